// Round 7
// baseline (768.776 us; speedup 1.0000x reference)
//
#include <hip/hip_runtime.h>

#define HID 128
#define CELLS 98304
#define NE 250000
#define NSTEPS 2
#define NWIN 3912  // 64-edge windows per edge type = 489 blocks * 8 waves

typedef __attribute__((ext_vector_type(8))) short short8;
typedef __attribute__((ext_vector_type(4))) float f32x4;
typedef __attribute__((ext_vector_type(4))) unsigned int u32x4;
typedef unsigned short u16;

// pi permutation: pi-slot s <-> natural col permf(s)
__device__ __forceinline__ int permf(int s) { return ((s & 7) << 4) | (s >> 3); }
// m storage position p: half = p>>6, lane = p&63,
// pi-slot = (lane>>2)*8 + half*4 + (lane&3); natural col = permf(slot)
__device__ __forceinline__ int nat_of_pos(int p) {
  int l = p & 63, hf = p >> 6;
  int slot = ((l >> 2) << 3) + (hf << 2) + (l & 3);
  return ((slot & 7) << 4) | (slot >> 3);
}

__device__ __forceinline__ u16 f2bf(float f) {
  unsigned int u = __builtin_bit_cast(unsigned int, f);
  u += 0x7fffu + ((u >> 16) & 1u);
  return (u16)(u >> 16);
}
__device__ __forceinline__ float bf2f(u16 s) {
  unsigned int u = ((unsigned int)s) << 16;
  return __builtin_bit_cast(float, u);
}
// packed f32x2 -> bf16x2 (RNE), lo -> D[15:0], hi -> D[31:16]
__device__ __forceinline__ unsigned int cvtpk_bf16(float lo, float hi) {
  unsigned int r;
  asm("v_cvt_pk_bf16_f32 %0, %1, %2" : "=v"(r) : "v"(lo), "v"(hi));
  return r;
}
__device__ __forceinline__ float sigm(float x) { return 1.f / (1.f + __expf(-x)); }
__device__ __forceinline__ float tanha(float x) { return 1.f - 2.f / (__expf(2.f * x) + 1.f); }

// zero-register DMA: 16B per lane, global(per-lane addr) -> LDS (wave-uniform base + lane*16)
__device__ __forceinline__ void gload_lds16(const u16* g, u16* l) {
  __builtin_amdgcn_global_load_lds(
      (const __attribute__((address_space(1))) unsigned int*)(const void*)g,
      (__attribute__((address_space(3))) unsigned int*)(void*)l, 16, 0, 0);
}

// cooperative 16KB weight-chunk stage: 512 threads x 2 insts x 16B, linear
__device__ __forceinline__ void stage_w(const u16* __restrict__ ws, u16* wl, int w, int lane) {
  #pragma unroll
  for (int i = 0; i < 2; ++i)
    gload_lds16(ws + i * 4096 + w * 512 + lane * 8, wl + i * 4096 + w * 512);
}

// ---------------- prep: bf16-convert weights ----------------
// Wpb: [o=(et*2+kind)*128+slot][k=128] -- L0 factorized: kind 0 = Ws (src cols 0..127),
//   kind 1 = Wd (dst cols 128..255); OUT feature pi-permuted (slot s -> natural permf(s)),
//   K natural (h order).
// W123b: [l-1][et][half hh][n][s=64], per-chunk XOR swizzle, K pi-permuted (tile order).
__global__ void prep_kernel(
    const float* __restrict__ W0, const float* __restrict__ W1,
    const float* __restrict__ W2, const float* __restrict__ W3,
    const float* __restrict__ b0, const float* __restrict__ b1,
    const float* __restrict__ b2, const float* __restrict__ b3,
    const float* __restrict__ Wih, const float* __restrict__ Whh,
    const float* __restrict__ embed, const float* __restrict__ sw,
    u16* __restrict__ Wpb, u16* __restrict__ W123b,
    u16* __restrict__ Wcb, float* __restrict__ bp,
    u16* __restrict__ embp, float* __restrict__ swp)
{
  int idx = blockIdx.x * 256 + threadIdx.x;
  if (idx < 65536) {  // Wpb proj weights (512 outs x 128 k)
    int o = idx >> 7, k = idx & 127;
    int et = o >> 8, kind = (o >> 7) & 1, slot = o & 127;
    Wpb[idx] = f2bf(W0[(et * 128 + permf(slot)) * 256 + kind * 128 + k]);
    return;
  }
  idx -= 65536;
  if (idx < 98304) {  // W123b swizzled half-chunks, K pi-permuted
    int which = idx >> 15, r = idx & 32767;
    int et = r >> 14, hh = (r >> 13) & 1, n = (r >> 6) & 127, s = r & 63;
    int g = s >> 3, j = s & 7;
    int gn = g ^ (n & 7);
    const float* W = which == 0 ? W1 : (which == 1 ? W2 : W3);
    W123b[which * 32768 + r] = f2bf(W[(et * 128 + n) * 128 + permf(hh * 64 + gn * 8 + j)]);
    return;
  }
  idx -= 98304;
  if (idx < 262144) {  // Wcat [n=512][k=512] = [Wih(x|m0|m1)|Whh]; m-blocks K in m-storage order
    int s = idx & 511, n = idx >> 9;
    int blk = s >> 7, s7 = s & 127;
    int k7 = (blk == 1 || blk == 2) ? nat_of_pos(s7) : s7;  // x / rh natural
    float v = (blk < 3) ? Wih[n * 384 + blk * 128 + k7] : Whh[n * 128 + k7];
    Wcb[idx] = f2bf(v);
    return;
  }
  idx -= 262144;
  if (idx < 1024) {  // biases [layer 0..3][et][slot] pi-order
    int l = idx >> 8, r = idx & 255;
    int et = r >> 7, s = r & 127;
    const float* b = l == 0 ? b0 : (l == 1 ? b1 : (l == 2 ? b2 : b3));
    bp[idx] = b[et * 128 + permf(s)];
    return;
  }
  idx -= 1024;
  if (idx < 384) {  // embed natural bf16
    embp[idx] = f2bf(embed[idx]);
    return;
  }
  idx -= 384;
  if (idx < 128) swp[idx] = sw[idx];
}

// ---------------- init: x = embed[q] (natural, bf16), h = x (rc untouched:
// step 0 never reads it) ----------------
__global__ void init_kernel(const int* __restrict__ q, const u16* __restrict__ embp,
                            u16* __restrict__ xb, u16* __restrict__ h)
{
  int idx = blockIdx.x * 256 + threadIdx.x;
  int c = idx >> 7, s = idx & 127;
  u16 v = embp[q[c] * 128 + s];
  xb[idx] = v;
  h[idx] = v;
}

// ---------------- dst-sort pipeline: hist -> scan (2-level) -> scatter ----------------
__global__ void hist_kernel(const int* __restrict__ edst, int* __restrict__ counts)
{
  int idx = blockIdx.x * 256 + threadIdx.x;
  if (idx >= 2 * NE) return;
  int et = (idx >= NE) ? 1 : 0;
  atomicAdd(&counts[et * CELLS + edst[idx]], 1);
}

__global__ void scan1_kernel(const int* __restrict__ counts, int* __restrict__ S,
                             int* __restrict__ btot)
{
  __shared__ int sh[1024];
  const int t = threadIdx.x, b = blockIdx.x;
  const int i = b * 1024 + t;
  int v = counts[i];
  sh[t] = v;
  __syncthreads();
  int acc = v;
  for (int off = 1; off < 1024; off <<= 1) {
    int add = (t >= off) ? sh[t - off] : 0;
    __syncthreads();
    acc += add;
    sh[t] = acc;
    __syncthreads();
  }
  S[i] = acc - v;  // block-local exclusive
  if (t == 1023) btot[b] = acc;
}

__global__ void scan2_kernel(const int* __restrict__ btot, int* __restrict__ boffs,
                             int* __restrict__ S)
{
  __shared__ int sh[256];
  const int t = threadIdx.x;
  int v = (t < 192) ? btot[t] : 0;
  sh[t] = v;
  __syncthreads();
  int acc = v;
  for (int off = 1; off < 256; off <<= 1) {
    int add = (t >= off) ? sh[t - off] : 0;
    __syncthreads();
    acc += add;
    sh[t] = acc;
    __syncthreads();
  }
  if (t < 192) boffs[t] = acc - v;
  if (t == 0) S[2 * CELLS] = 2 * NE;
}

__global__ void scan3_kernel(int* __restrict__ S, const int* __restrict__ boffs)
{
  const int i = blockIdx.x * 1024 + threadIdx.x;
  S[i] += boffs[blockIdx.x];
}

__global__ void scatter_kernel(const int* __restrict__ esrc, const int* __restrict__ edst,
                               const int* __restrict__ S, int* __restrict__ fill,
                               int* __restrict__ ssrc, int* __restrict__ sdst)
{
  int idx = blockIdx.x * 256 + threadIdx.x;
  if (idx >= 2 * NE) return;
  int et = (idx >= NE) ? 1 : 0;
  int d = edst[idx];
  int pos = atomicAdd(&fill[et * CELLS + d], 1);
  int slot = S[et * CELLS + d] - et * NE + pos;  // et-local sorted slot
  sdst[et * NE + slot] = d;
  ssrc[et * NE + slot] = esrc[idx];
}

// ---------------- proj: per-cell L0 projections ps = h@Ws^T, pd = h@Wd^T ---------------
// R7: L0 factorization. Replaces 33 GFLOP of gather-fed per-edge L0 MFMA in msg with
// 12.9 GFLOP of dense GEMM here (lstm-shaped: 64-cell blocks, 8 waves x 64 outs).
// Output pp[(et*2+kind)][cell][slot] bf16, OUT features pi-permuted so msg's add-pass
// writes the L1 tile directly in tile slot order.
__launch_bounds__(512, 4)
__global__ void proj_kernel(const u16* __restrict__ h, const u16* __restrict__ Wpb,
                            u16* __restrict__ pp)
{
  __shared__ u16 at[64 * 128];  // 16KB A-tile, XOR-swizzled
  const int tid = threadIdx.x;
  const int cb = blockIdx.x * 64;
  for (int base = tid * 8; base < 64 * 128; base += 4096) {
    const int cl = base >> 7, s = base & 127;
    short8 t = *(const short8*)(h + (size_t)(cb + cl) * 128 + s);
    const int blk = s >> 3;
    *(short8*)(at + cl * 128 + ((blk ^ (cl & 15)) << 3)) = t;
  }
  __syncthreads();

  const int w = tid >> 6, lane = tid & 63, q = lane >> 4, c = lane & 15;
  const f32x4 zf = {0.f, 0.f, 0.f, 0.f};
  f32x4 acc[4][4];
  #pragma unroll
  for (int mt = 0; mt < 4; ++mt)
    #pragma unroll
    for (int no = 0; no < 4; ++no) acc[mt][no] = zf;

  #pragma unroll
  for (int ks = 0; ks < 4; ++ks) {
    const int kq = ks * 32 + q * 8;
    const int blk = kq >> 3;  // 0..15
    short8 a[4], b[4];
    #pragma unroll
    for (int mt = 0; mt < 4; ++mt)
      a[mt] = *(const short8*)(at + (mt * 16 + c) * 128 + ((blk ^ c) << 3));
    #pragma unroll
    for (int no = 0; no < 4; ++no)
      b[no] = *(const short8*)(Wpb + (size_t)(w * 64 + no * 16 + c) * 128 + kq);
    #pragma unroll
    for (int mt = 0; mt < 4; ++mt)
      #pragma unroll
      for (int no = 0; no < 4; ++no)
        acc[mt][no] = __builtin_amdgcn_mfma_f32_16x16x32_bf16(a[mt], b[no], acc[mt][no], 0, 0, 0);
  }

  // out o = w*64 + no*16 + c -> group g2 = w>>1 (= et*2+kind), slot = (w&1)*64 + no*16 + c
  const int g2 = w >> 1;
  const int sbase = (w & 1) * 64;
  #pragma unroll
  for (int mt = 0; mt < 4; ++mt) {
    #pragma unroll
    for (int r = 0; r < 4; ++r) {
      const int cell = cb + mt * 16 + 4 * q + r;
      u16* op = pp + ((size_t)g2 * CELLS + cell) * 128 + sbase + c;
      #pragma unroll
      for (int no = 0; no < 4; ++no) op[no * 16] = f2bf(acc[mt][no][r]);
    }
  }
}

// bias + relu + pack-transpose into swizzled per-wave LDS A-tile (pitch 128, 8-col XOR swizzle)
__device__ __forceinline__ void bias_relu_store(f32x4 (&acc)[4][8], const float* __restrict__ bl,
                                                u16* __restrict__ ab, int q, int c)
{
  float bias[8];
  #pragma unroll
  for (int j = 0; j < 8; ++j) bias[j] = bl[c * 8 + j];
  #pragma unroll
  for (int mt = 0; mt < 4; ++mt) {
    #pragma unroll
    for (int r = 0; r < 4; ++r) {
      const int rowl = mt * 16 + 4 * q + r;
      u32x4 t;
      #pragma unroll
      for (int p = 0; p < 4; ++p) {
        float v0 = acc[mt][2 * p][r] + bias[2 * p];
        float v1 = acc[mt][2 * p + 1][r] + bias[2 * p + 1];
        v0 = v0 > 0.f ? v0 : 0.f;
        v1 = v1 > 0.f ? v1 : 0.f;
        t[p] = cvtpk_bf16(v0, v1);
      }
      *(u32x4*)(ab + rowl * 128 + ((c ^ (rowl & 15)) << 3)) = t;
    }
  }
}

// ---------------- fused 3-layer edge MLP (L1-3) + sorted segmented-sum scatter --------
// R7: L0 moved to proj_kernel. msg now: DMA-stage ps[src] into the tile, register-gather
// pd[dst], add-pass z = relu(ps+pd+b0) in-place (wave-private, in-order DS, no barrier),
// then 6 pipelined weight chunks (L1..L3 x 2 K-halves) with the R5 dbuf schedule.
// No global loads inside the K-loop anymore -> each chunk drain waits ONLY on its stage.
__launch_bounds__(512, 2)
__global__ void msg_kernel(
    const u16* __restrict__ pp,
    const int* __restrict__ ssrc, const int* __restrict__ sdst,
    const int* __restrict__ S,
    const u16* __restrict__ W123b,
    const float* __restrict__ bp,
    u16* __restrict__ m0, u16* __restrict__ m1,
    int* __restrict__ side_dst, float* __restrict__ side_part)
{
  __shared__ u16 abuf[8][64 * 128];   // 128KB: wave-private A-tiles, XOR-swizzled
  __shared__ u16 wbuf[2][128 * 64];   // 32KB: double-buffered weight chunk [n=128][k=64]
  const int et = blockIdx.y;
  const int tid = threadIdx.x;
  const int w = tid >> 6, lane = tid & 63, q = lane >> 4, c = lane & 15;
  const int ebase = blockIdx.x * 512 + w * 64;  // et-local sorted slot base for this wave
  const int win = blockIdx.x * 8 + w;
  const int* __restrict__ src = ssrc + et * NE;
  const int* __restrict__ dst = sdst + et * NE;
  const u16* __restrict__ psb = pp + (size_t)(et * 2 + 0) * CELLS * 128;
  const u16* __restrict__ pdb = pp + (size_t)(et * 2 + 1) * CELLS * 128;
  u16* __restrict__ msgs = (et == 0) ? m0 : m1;
  u16* ab = abuf[w];

  // first weight chunk (L1 hh=0) into wbuf[0] -- issue before the gather chains
  stage_w(W123b + et * 16384, wbuf[0], w, lane);

  // per-lane src row for DMA staging
  int eS = ebase + lane;
  if (eS >= NE) eS = NE - 1;
  const int srow = src[eS];

  // run structure (wave-uniform masks). Cross-lane ops unconditional.
  const int eL = ebase + lane;
  const int dval = (eL < NE) ? dst[eL] : -1;
  int rpS = 0, rpE = 0;
  if (dval >= 0) {
    rpS = S[et * CELLS + dval] - et * NE;
    rpE = S[et * CELLS + dval + 1] - et * NE;
  }
  const int dlagged = __shfl_up(dval, 1);          // all 64 lanes active
  const bool headp = (lane == 0) | (dval != dlagged);
  const unsigned long long tails = (__ballot(headp) >> 1) | (1ull << 63);
  const unsigned long long intmask = __ballot(dval >= 0 && rpS >= ebase && rpE <= ebase + 64);

  // issue 16 zero-register DMA gathers: ps[src] rows -> own swizzled LDS tile.
  // position (row r, group cg) holds slot-group cg ^ (r&15).
  #pragma unroll
  for (int i = 0; i < 16; ++i) {
    const int r = i * 4 + (lane >> 4);
    const int grow = __shfl(srow, r);
    const int cg = lane & 15;
    gload_lds16(psb + (size_t)grow * 128 + ((cg ^ (r & 15)) << 3), ab + i * 512);
  }

  // register-gather pd[dst] rows, same (r, cg) layout (16 x short8, freed after add-pass)
  short8 pdr[16];
  #pragma unroll
  for (int i = 0; i < 16; ++i) {
    const int r = i * 4 + (lane >> 4);
    int drow = __shfl(dval, r);
    drow = drow < 0 ? 0 : drow;  // OOB rows: garbage isolated by run tails, never stored
    pdr[i] = *(const short8*)(pdb + (size_t)drow * 128 + ((lane & 15) << 3));
  }

  asm volatile("s_waitcnt vmcnt(0)" ::: "memory");  // ps DMAs + pd gathers + chunk 0
  __syncthreads();

  // add-pass: z = relu(ps + pd + b0) in-place in own tile (in-order DS, no barrier)
  {
    const int cg = lane & 15;
    float bz[8];
    #pragma unroll
    for (int j = 0; j < 8; ++j) bz[j] = bp[et * 128 + cg * 8 + j];
    #pragma unroll
    for (int i = 0; i < 16; ++i) {
      const int r = i * 4 + (lane >> 4);
      u16* p = ab + r * 128 + ((cg ^ (r & 15)) << 3);
      short8 sv = *(const short8*)p;
      u32x4 o;
      #pragma unroll
      for (int x = 0; x < 4; ++x) {
        float v0 = bf2f((u16)sv[2 * x])     + bf2f((u16)pdr[i][2 * x])     + bz[2 * x];
        float v1 = bf2f((u16)sv[2 * x + 1]) + bf2f((u16)pdr[i][2 * x + 1]) + bz[2 * x + 1];
        v0 = v0 > 0.f ? v0 : 0.f;
        v1 = v1 > 0.f ? v1 : 0.f;
        o[x] = cvtpk_bf16(v0, v1);
      }
      *(u32x4*)p = o;
    }
  }

  const f32x4 zf = {0.f, 0.f, 0.f, 0.f};
  f32x4 acc[4][8];
  #pragma unroll
  for (int mt = 0; mt < 4; ++mt)
    #pragma unroll
    for (int nt = 0; nt < 8; ++nt) acc[mt][nt] = zf;

  // ---- 6-chunk pipelined K-loop (L1..L3 x two K-halves) ----
  #pragma unroll 1
  for (int i = 0; i < 6; ++i) {
    if (i < 5) {
      const int j = i + 1;
      stage_w(W123b + (j >> 1) * 32768 + et * 16384 + (j & 1) * 8192, wbuf[j & 1], w, lane);
    }
    if (i == 2 || i == 4) {  // flush previous layer's output (bias of that layer)
      bias_relu_store(acc, bp + (i >> 1) * 256 + et * 128, ab, q, c);
      #pragma unroll
      for (int mt = 0; mt < 4; ++mt)
        #pragma unroll
        for (int nt = 0; nt < 8; ++nt) acc[mt][nt] = zf;
    }
    const u16* wb = wbuf[i & 1];
    #pragma unroll
    for (int ks = 0; ks < 2; ++ks) {
      const int blk = (i & 1) * 8 + ks * 4 + q;
      short8 a[4], b[8];
      #pragma unroll
      for (int mt = 0; mt < 4; ++mt) {
        const int row = mt * 16 + c;
        a[mt] = *(const short8*)(ab + row * 128 + ((blk ^ c) << 3));
      }
      #pragma unroll
      for (int nt = 0; nt < 8; ++nt)
        b[nt] = *(const short8*)(wb + (nt * 16 + c) * 64 + (((ks * 4 + q) ^ (c & 7)) << 3));
      #pragma unroll
      for (int mt = 0; mt < 4; ++mt)
        #pragma unroll
        for (int nt = 0; nt < 8; ++nt)
          acc[mt][nt] = __builtin_amdgcn_mfma_f32_16x16x32_bf16(a[mt], b[nt], acc[mt][nt], 0, 0, 0);
    }
    // drain only waits on next chunk's stage (no other VMEM in flight)
    asm volatile("s_waitcnt vmcnt(0)" ::: "memory");
    __syncthreads();
  }

  // layer-3 epilogue: +bias into fp32 fab (two 64-feature passes), column scan; interior
  // flush = 128B coalesced bf16 store; boundary flush = fp32 partial to side buffer.
  float bias[8];
  #pragma unroll
  for (int j = 0; j < 8; ++j) bias[j] = bp[3 * 256 + et * 128 + c * 8 + j];

  float* fab = (float*)ab;  // 64 rows x 64 feature-slots fp32 (16KB, wave-private)
  #pragma unroll
  for (int half = 0; half < 2; ++half) {
    #pragma unroll
    for (int mt = 0; mt < 4; ++mt) {
      #pragma unroll
      for (int r = 0; r < 4; ++r) {
        const int row = mt * 16 + 4 * q + r;
        f32x4 t;
        #pragma unroll
        for (int nti = 0; nti < 4; ++nti)
          t[nti] = acc[mt][half * 4 + nti][r] + bias[half * 4 + nti];
        *(f32x4*)(fab + row * 64 + c * 4) = t;
      }
    }
    float run = 0.f;
    int jstart = 0;
    #pragma unroll 1
    for (int jb = 0; jb < 64; jb += 8) {
      #pragma unroll
      for (int u = 0; u < 8; ++u) {
        const int j = jb + u;
        run += fab[j * 64 + lane];
        if ((tails >> j) & 1) {  // wave-uniform flush at run tail
          const int d = __builtin_amdgcn_readlane(dval, j);
          if (d >= 0) {
            if ((intmask >> j) & 1) {
              msgs[(size_t)d * HID + half * 64 + lane] = f2bf(run);
            } else {
              const int slot = (jstart == 0) ? 0 : 1;  // only first/last runs can straddle
              const size_t sb = ((size_t)et * NWIN + win) * 2 + slot;
              side_part[sb * 128 + half * 64 + lane] = run;
              if (lane == 0 && half == 0) side_dst[sb] = d;
            }
          }
          run = 0.f;
          jstart = j + 1;
        }
      }
    }
  }
}

// ---------------- boundary fixup: owner window sums fp32 partials, writes bf16 m ------
__global__ void fixup_kernel(const int* __restrict__ S,
                             const int* __restrict__ side_dst,
                             const float* __restrict__ side_part,
                             u16* __restrict__ m0, u16* __restrict__ m1)
{
  const int b = blockIdx.x;           // et*NWIN + win
  const int et = b / NWIN, win = b - et * NWIN;
  const int t = threadIdx.x;          // 0..127
  u16* __restrict__ m = et ? m1 : m0;
  #pragma unroll
  for (int s = 0; s < 2; ++s) {
    const int d = side_dst[b * 2 + s];
    if (d < 0) continue;
    const int r0 = S[et * CELLS + d] - et * NE;
    if ((r0 >> 6) != win) continue;   // not the owner window (64-edge windows)
    const int w1 = (S[et * CELLS + d + 1] - et * NE - 1) >> 6;
    float sum = 0.f;
    for (int wi = win; wi <= w1; ++wi) {
      const int base = (et * NWIN + wi) * 2;
      if (side_dst[base + 0] == d) sum += side_part[(size_t)(base + 0) * 128 + t];
      if (side_dst[base + 1] == d) sum += side_part[(size_t)(base + 1) * 128 + t];
    }
    m[(size_t)d * HID + t] = f2bf(sum);
  }
}

// ---------------- fused LSTM: gates GEMM (K=512) + in-register activations + score -------
// block: 8 waves, 64 cells. Wave wf owns feature cols [wf*16, wf*16+16) for ALL 4 gates.
// rc is bf16; step 0 skips the rc read (known zero); final step skips rc/h writes.
__launch_bounds__(512, 4)
__global__ void lstm_kernel(
    const int step,
    const u16* __restrict__ xb, const u16* __restrict__ mm0, const u16* __restrict__ mm1,
    u16* __restrict__ h, u16* __restrict__ rc,
    const u16* __restrict__ Wcb, const float* __restrict__ swp,
    float* __restrict__ out)
{
  __shared__ u16 at[64 * 512];  // 64KB: A-tile, later reused for score partials
  const int tid = threadIdx.x;
  const int cb = blockIdx.x * 64;

  // stage A = [x | m0 | m1 | rh] bf16; m already bf16 in storage order (Wcb K matches)
  for (int base = tid * 8; base < 64 * 512; base += 4096) {
    const int cl = base >> 9, s = base & 511;
    const int cell = cb + cl;
    short8 t;
    if (s < 128) {
      t = *(const short8*)(xb + cell * 128 + s);
    } else if (s < 384) {
      const u16* mp = (s < 256 ? mm0 : mm1) + cell * 128 + (s & 127);
      t = *(const short8*)(mp);
    } else if (step == 0) {
      #pragma unroll
      for (int j = 0; j < 8; ++j) t[j] = 0;
    } else {
      t = *(const short8*)(h + cell * 128 + (s & 127));
    }
    const int blk = s >> 3;
    const int blks = (blk & 48) | ((blk ^ cl) & 15);
    *(short8*)(at + cl * 512 + blks * 8) = t;
  }
  __syncthreads();

  const int w = tid >> 6, lane = tid & 63, q = lane >> 4, c = lane & 15;
  const int wf = w;  // feature-16 group
  const f32x4 zf = {0.f, 0.f, 0.f, 0.f};
  f32x4 acc[4][4];  // [cell-tile][gate]
  #pragma unroll
  for (int mt = 0; mt < 4; ++mt)
    #pragma unroll
    for (int g = 0; g < 4; ++g) acc[mt][g] = zf;

  #pragma unroll
  for (int ks = 0; ks < 16; ++ks) {
    const int kq = ks * 32 + q * 8;
    const int blk = kq >> 3;
    short8 a[4], b[4];
    #pragma unroll
    for (int mt = 0; mt < 4; ++mt) {
      const int row = mt * 16 + c;
      const int blks = (blk & 48) | ((blk ^ c) & 15);
      a[mt] = *(const short8*)(at + row * 512 + blks * 8);
    }
    #pragma unroll
    for (int g = 0; g < 4; ++g)
      b[g] = *(const short8*)(Wcb + (g * 128 + wf * 16 + c) * 512 + kq);
    #pragma unroll
    for (int mt = 0; mt < 4; ++mt)
      #pragma unroll
      for (int g = 0; g < 4; ++g)
        acc[mt][g] = __builtin_amdgcn_mfma_f32_16x16x32_bf16(a[mt], b[g], acc[mt][g], 0, 0, 0);
  }
  __syncthreads();  // tile reads done everywhere; safe to reuse for score partials

  // in-register LSTM epilogue: lane (q,c) per (mt,r): cell = mt*16+4q+r, feat = wf*16+c
  const float swc = swp[wf * 16 + c];
  const bool last = (step == NSTEPS - 1);
  float* pt = (float*)at;  // [8 waves][64 cells] score partials
  #pragma unroll
  for (int mt = 0; mt < 4; ++mt) {
    #pragma unroll
    for (int r = 0; r < 4; ++r) {
      const int cl = mt * 16 + 4 * q + r;
      const int cell = cb + cl;
      const float ig = sigm(acc[mt][0][r]);
      const float fg = sigm(acc[mt][1][r]);
      const float gg = tanha(acc[mt][2][r]);
      const float og = sigm(acc[mt][3][r]);
      u16* rcp = rc + (size_t)cell * HID + wf * 16 + c;
      const float c0 = (step == 0) ? 0.f : bf2f(rcp[0]);
      const float nc = fg * c0 + ig * gg;
      const float nhv = og * tanha(nc);
      if (!last) {
        rcp[0] = f2bf(nc);
        h[(size_t)cell * HID + wf * 16 + c] = f2bf(nhv);
      }
      float v = nhv * swc;  // score partial, reduce over c (16 feats)
      v += __shfl_xor(v, 1); v += __shfl_xor(v, 2);
      v += __shfl_xor(v, 4); v += __shfl_xor(v, 8);
      if (c == 0) pt[wf * 64 + cl] = v;
    }
  }
  __syncthreads();
  if (tid < 64) {
    float s = 0.f;
    #pragma unroll
    for (int ww = 0; ww < 8; ++ww) s += pt[ww * 64 + tid];
    out[step * CELLS + cb + tid] = s;
  }
}

extern "C" void kernel_launch(void* const* d_in, const int* in_sizes, int n_in,
                              void* d_out, int out_size, void* d_ws, size_t ws_size,
                              hipStream_t stream)
{
  const int* q      = (const int*)d_in[0];
  const int* esrc   = (const int*)d_in[1];
  const int* edst   = (const int*)d_in[2];
  const float* embed= (const float*)d_in[3];
  const float* W0   = (const float*)d_in[4];
  const float* b0   = (const float*)d_in[5];
  const float* W1   = (const float*)d_in[6];
  const float* b1   = (const float*)d_in[7];
  const float* W2   = (const float*)d_in[8];
  const float* b2   = (const float*)d_in[9];
  const float* W3   = (const float*)d_in[10];
  const float* b3   = (const float*)d_in[11];
  const float* Wih  = (const float*)d_in[12];
  const float* Whh  = (const float*)d_in[13];
  const float* sw   = (const float*)d_in[14];

  char* ws = (char*)d_ws;
  size_t off = 0;
  auto alloc = [&](size_t bytes) {
    void* p = ws + off;
    off += (bytes + 255) & ~(size_t)255;
    return p;
  };
  u16*   h    = (u16*)  alloc((size_t)CELLS * HID * 2);
  u16*   xb   = (u16*)  alloc((size_t)CELLS * HID * 2);
  u16*   rc   = (u16*)  alloc((size_t)CELLS * HID * 2);  // bf16 carry
  u16*   m0   = (u16*)  alloc((size_t)CELLS * HID * 2);  // bf16; m1 contiguous after
  u16*   m1   = (u16*)  alloc((size_t)CELLS * HID * 2);
  u16*   pp   = (u16*)  alloc((size_t)4 * CELLS * 128 * 2);  // [et*2+kind][cell][slot]
  u16*   Wpb  = (u16*)  alloc(512 * 128 * 2);
  u16*   W123b= (u16*)  alloc((size_t)3 * 2 * 128 * 128 * 2);  // layers 1..3 contiguous
  u16*   Wcb  = (u16*)  alloc(512 * 512 * 2);
  float* bp   = (float*)alloc(4 * 256 * 4);
  u16*   embp = (u16*)  alloc(384 * 2);
  float* swp  = (float*)alloc(128 * 4);
  // sort workspace
  int*   counts = (int*)alloc((size_t)2 * CELLS * 4);
  int*   Sarr   = (int*)alloc(((size_t)2 * CELLS + 1) * 4);
  int*   fill   = (int*)alloc((size_t)2 * CELLS * 4);
  int*   btot   = (int*)alloc(192 * 4);
  int*   boffs  = (int*)alloc(192 * 4);
  int*   ssrc   = (int*)alloc((size_t)2 * NE * 4);
  int*   sdst   = (int*)alloc((size_t)2 * NE * 4);
  // boundary side buffers
  int*   side_dst  = (int*)  alloc((size_t)2 * NWIN * 2 * 4);
  float* side_part = (float*)alloc((size_t)2 * NWIN * 2 * 128 * 4);

  prep_kernel<<<1670, 256, 0, stream>>>(W0, W1, W2, W3, b0, b1, b2, b3, Wih, Whh, embed, sw,
                                        Wpb, W123b, Wcb, bp, embp, swp);
  init_kernel<<<(CELLS * HID) / 256, 256, 0, stream>>>(q, embp, xb, h);

  // dst-sort both edge types
  hipMemsetAsync(counts, 0, (size_t)2 * CELLS * 4, stream);
  hipMemsetAsync(fill, 0, (size_t)2 * CELLS * 4, stream);
  hist_kernel<<<(2 * NE + 255) / 256, 256, 0, stream>>>(edst, counts);
  scan1_kernel<<<192, 1024, 0, stream>>>(counts, Sarr, btot);
  scan2_kernel<<<1, 256, 0, stream>>>(btot, boffs, Sarr);
  scan3_kernel<<<192, 1024, 0, stream>>>(Sarr, boffs);
  scatter_kernel<<<(2 * NE + 255) / 256, 256, 0, stream>>>(esrc, edst, Sarr, fill, ssrc, sdst);

  // m zeroing hoisted out of the step loop: every dst with >=1 edge gets its full row
  // rewritten each step (interior flush or fixup); zero-degree rows stay zero. side_dst
  // values are step-invariant (same sorted graph), so one 0xFF fill suffices.
  hipMemsetAsync(m0, 0, (size_t)2 * CELLS * HID * 2, stream);        // m0+m1 (bf16)
  hipMemsetAsync(side_dst, 0xFF, (size_t)2 * NWIN * 2 * 4, stream);  // dst = -1

  for (int step = 0; step < NSTEPS; ++step) {
    proj_kernel<<<CELLS / 64, 512, 0, stream>>>(h, Wpb, pp);
    msg_kernel<<<dim3((NE + 511) / 512, 2), 512, 0, stream>>>(pp, ssrc, sdst, Sarr,
                                                              W123b, bp,
                                                              m0, m1, side_dst, side_part);
    fixup_kernel<<<2 * NWIN, 128, 0, stream>>>(Sarr, side_dst, side_part, m0, m1);
    lstm_kernel<<<CELLS / 64, 512, 0, stream>>>(step, xb, m0, m1, h, rc, Wcb, swp, (float*)d_out);
  }
}

// Round 8
// 724.751 us; speedup vs baseline: 1.0607x; 1.0607x over previous
//
#include <hip/hip_runtime.h>

#define HID 128
#define CELLS 98304
#define NE 250000
#define NSTEPS 2
#define NWIN 7816  // 32-edge windows per edge type = 1954 blocks * 4 waves

typedef __attribute__((ext_vector_type(8))) short short8;
typedef __attribute__((ext_vector_type(4))) float f32x4;
typedef __attribute__((ext_vector_type(4))) unsigned int u32x4;
typedef unsigned short u16;

// pi permutation: pi-slot s <-> natural col permf(s)
__device__ __forceinline__ int permf(int s) { return ((s & 7) << 4) | (s >> 3); }
// m storage position p: half = p>>6, lane = p&63,
// pi-slot = (lane>>2)*8 + half*4 + (lane&3); natural col = permf(slot)
__device__ __forceinline__ int nat_of_pos(int p) {
  int l = p & 63, hf = p >> 6;
  int slot = ((l >> 2) << 3) + (hf << 2) + (l & 3);
  return ((slot & 7) << 4) | (slot >> 3);
}

__device__ __forceinline__ u16 f2bf(float f) {
  unsigned int u = __builtin_bit_cast(unsigned int, f);
  u += 0x7fffu + ((u >> 16) & 1u);
  return (u16)(u >> 16);
}
__device__ __forceinline__ float bf2f(u16 s) {
  unsigned int u = ((unsigned int)s) << 16;
  return __builtin_bit_cast(float, u);
}
// packed f32x2 -> bf16x2 (RNE), lo -> D[15:0], hi -> D[31:16]
__device__ __forceinline__ unsigned int cvtpk_bf16(float lo, float hi) {
  unsigned int r;
  asm("v_cvt_pk_bf16_f32 %0, %1, %2" : "=v"(r) : "v"(lo), "v"(hi));
  return r;
}
__device__ __forceinline__ float sigm(float x) { return 1.f / (1.f + __expf(-x)); }
__device__ __forceinline__ float tanha(float x) { return 1.f - 2.f / (__expf(2.f * x) + 1.f); }

// zero-register DMA: 16B per lane, global(per-lane addr) -> LDS (wave-uniform base + lane*16)
__device__ __forceinline__ void gload_lds16(const u16* g, u16* l) {
  __builtin_amdgcn_global_load_lds(
      (const __attribute__((address_space(1))) unsigned int*)(const void*)g,
      (__attribute__((address_space(3))) unsigned int*)(void*)l, 16, 0, 0);
}

// cooperative 16KB weight-chunk stage: 256 threads x 4 insts x 16B, linear
__device__ __forceinline__ void stage_w(const u16* __restrict__ ws, u16* wl, int w, int lane) {
  #pragma unroll
  for (int i = 0; i < 4; ++i)
    gload_lds16(ws + i * 2048 + w * 512 + lane * 8, wl + i * 2048 + w * 512);
}

// ---------------- prep: bf16-convert weights ----------------
// W0b: [et][chunk t=0..3][n=128][s=64] -- K-chunks of 64, XOR-swizzled within chunk:
//   position group g' (0..7) of row n holds natural k-group g'^(n&7) of chunk t.
//   t=0,1: src half (k 0..127), t=2,3: dst half (k 128..255). Natural K (h order).
// W123b: [l-1][et][half hh][n][s=64], same per-chunk swizzle, K pi-permuted (tile order).
__global__ void prep_kernel(
    const float* __restrict__ W0, const float* __restrict__ W1,
    const float* __restrict__ W2, const float* __restrict__ W3,
    const float* __restrict__ b0, const float* __restrict__ b1,
    const float* __restrict__ b2, const float* __restrict__ b3,
    const float* __restrict__ Wih, const float* __restrict__ Whh,
    const float* __restrict__ embed, const float* __restrict__ sw,
    u16* __restrict__ W0b, u16* __restrict__ W123b,
    u16* __restrict__ Wcb, float* __restrict__ bp,
    u16* __restrict__ embp, float* __restrict__ swp)
{
  int idx = blockIdx.x * 256 + threadIdx.x;
  if (idx < 65536) {  // W0b swizzled chunks
    int et = idx >> 15, t = (idx >> 13) & 3, n = (idx >> 6) & 127, s = idx & 63;
    int g = s >> 3, j = s & 7;
    int gn = g ^ (n & 7);
    W0b[idx] = f2bf(W0[(et * 128 + n) * 256 + t * 64 + gn * 8 + j]);
    return;
  }
  idx -= 65536;
  if (idx < 98304) {  // W123b swizzled half-chunks, K pi-permuted
    int which = idx >> 15, r = idx & 32767;
    int et = r >> 14, hh = (r >> 13) & 1, n = (r >> 6) & 127, s = r & 63;
    int g = s >> 3, j = s & 7;
    int gn = g ^ (n & 7);
    const float* W = which == 0 ? W1 : (which == 1 ? W2 : W3);
    W123b[which * 32768 + r] = f2bf(W[(et * 128 + n) * 128 + permf(hh * 64 + gn * 8 + j)]);
    return;
  }
  idx -= 98304;
  if (idx < 262144) {  // Wcat [n=512][k=512] = [Wih(x|m0|m1)|Whh]; m-blocks K in m-storage order
    int s = idx & 511, n = idx >> 9;
    int blk = s >> 7, s7 = s & 127;
    int k7 = (blk == 1 || blk == 2) ? nat_of_pos(s7) : s7;  // x / rh natural
    float v = (blk < 3) ? Wih[n * 384 + blk * 128 + k7] : Whh[n * 128 + k7];
    Wcb[idx] = f2bf(v);
    return;
  }
  idx -= 262144;
  if (idx < 1024) {  // biases [layer 0..3][et][slot] pi-order
    int l = idx >> 8, r = idx & 255;
    int et = r >> 7, s = r & 127;
    const float* b = l == 0 ? b0 : (l == 1 ? b1 : (l == 2 ? b2 : b3));
    bp[idx] = b[et * 128 + permf(s)];
    return;
  }
  idx -= 1024;
  if (idx < 384) {  // embed natural bf16
    embp[idx] = f2bf(embed[idx]);
    return;
  }
  idx -= 384;
  if (idx < 128) swp[idx] = sw[idx];
}

// ---------------- init: x = embed[q] (natural, bf16), h = x (rc untouched:
// step 0 never reads it) ----------------
__global__ void init_kernel(const int* __restrict__ q, const u16* __restrict__ embp,
                            u16* __restrict__ xb, u16* __restrict__ h)
{
  int idx = blockIdx.x * 256 + threadIdx.x;
  int c = idx >> 7, s = idx & 127;
  u16 v = embp[q[c] * 128 + s];
  xb[idx] = v;
  h[idx] = v;
}

// ---------------- dst-sort pipeline: hist -> scan (2-level) -> scatter ----------------
__global__ void hist_kernel(const int* __restrict__ edst, int* __restrict__ counts)
{
  int idx = blockIdx.x * 256 + threadIdx.x;
  if (idx >= 2 * NE) return;
  int et = (idx >= NE) ? 1 : 0;
  atomicAdd(&counts[et * CELLS + edst[idx]], 1);
}

__global__ void scan1_kernel(const int* __restrict__ counts, int* __restrict__ S,
                             int* __restrict__ btot)
{
  __shared__ int sh[1024];
  const int t = threadIdx.x, b = blockIdx.x;
  const int i = b * 1024 + t;
  int v = counts[i];
  sh[t] = v;
  __syncthreads();
  int acc = v;
  for (int off = 1; off < 1024; off <<= 1) {
    int add = (t >= off) ? sh[t - off] : 0;
    __syncthreads();
    acc += add;
    sh[t] = acc;
    __syncthreads();
  }
  S[i] = acc - v;  // block-local exclusive
  if (t == 1023) btot[b] = acc;
}

__global__ void scan2_kernel(const int* __restrict__ btot, int* __restrict__ boffs,
                             int* __restrict__ S)
{
  __shared__ int sh[256];
  const int t = threadIdx.x;
  int v = (t < 192) ? btot[t] : 0;
  sh[t] = v;
  __syncthreads();
  int acc = v;
  for (int off = 1; off < 256; off <<= 1) {
    int add = (t >= off) ? sh[t - off] : 0;
    __syncthreads();
    acc += add;
    sh[t] = acc;
    __syncthreads();
  }
  if (t < 192) boffs[t] = acc - v;
  if (t == 0) S[2 * CELLS] = 2 * NE;
}

__global__ void scan3_kernel(int* __restrict__ S, const int* __restrict__ boffs)
{
  const int i = blockIdx.x * 1024 + threadIdx.x;
  S[i] += boffs[blockIdx.x];
}

__global__ void scatter_kernel(const int* __restrict__ esrc, const int* __restrict__ edst,
                               const int* __restrict__ S, int* __restrict__ fill,
                               int* __restrict__ ssrc, int* __restrict__ sdst)
{
  int idx = blockIdx.x * 256 + threadIdx.x;
  if (idx >= 2 * NE) return;
  int et = (idx >= NE) ? 1 : 0;
  int d = edst[idx];
  int pos = atomicAdd(&fill[et * CELLS + d], 1);
  int slot = S[et * CELLS + d] - et * NE + pos;  // et-local sorted slot
  sdst[et * NE + slot] = d;
  ssrc[et * NE + slot] = esrc[idx];
}

// bias + relu + pack-transpose into swizzled per-wave LDS A-tile (pitch 128, 8-col XOR
// swizzle). 32-edge window: acc[2][8], rows 0..31. Packed conversion via cvt_pk (R6).
__device__ __forceinline__ void bias_relu_store(f32x4 (&acc)[2][8], const float* __restrict__ bl,
                                                u16* __restrict__ ab, int q, int c)
{
  float bias[8];
  #pragma unroll
  for (int j = 0; j < 8; ++j) bias[j] = bl[c * 8 + j];
  #pragma unroll
  for (int mt = 0; mt < 2; ++mt) {
    #pragma unroll
    for (int r = 0; r < 4; ++r) {
      const int rowl = mt * 16 + 4 * q + r;
      u32x4 t;
      #pragma unroll
      for (int p = 0; p < 4; ++p) {
        float v0 = acc[mt][2 * p][r] + bias[2 * p];
        float v1 = acc[mt][2 * p + 1][r] + bias[2 * p + 1];
        v0 = v0 > 0.f ? v0 : 0.f;
        v1 = v1 > 0.f ? v1 : 0.f;
        t[p] = cvtpk_bf16(v0, v1);
      }
      *(u32x4*)(ab + rowl * 128 + ((c ^ (rowl & 15)) << 3)) = t;
    }
  }
}

// ---------------- fused 4-layer edge MLP + sorted segmented-sum scatter ----------------
// R7 post-mortem: L0 factorization was a wash (msg -20/step confirmed, but pp
// materialization +25..50/step) -> REVERTED to R6's inline-L0 pipeline. R7's real
// finding: cost scales with chunk-phase count -- ~10k cy per phase for ~1k cy of work,
// because 160KB LDS -> 1 block/CU means every barrier's tail latency idles the whole CU
// (convoy). R(this): TWO barrier domains per CU. 4-wave blocks, 32-edge windows:
// abuf 4x8KB + wbuf[2] 32KB = 64KB/block -> 2 blocks/CU; one block's compute fills the
// other's barrier/stage stalls. Same chunk schedule (10 chunks, 2-deep wbuf pipeline),
// same masks (32-edge variant validated in R2), acc[2][8].
__launch_bounds__(256, 2)
__global__ void msg_kernel(
    const u16* __restrict__ h,
    const int* __restrict__ ssrc, const int* __restrict__ sdst,
    const int* __restrict__ S,
    const u16* __restrict__ W0b, const u16* __restrict__ W123b,
    const float* __restrict__ bp,
    u16* __restrict__ m0, u16* __restrict__ m1,
    int* __restrict__ side_dst, float* __restrict__ side_part)
{
  __shared__ u16 abuf[4][32 * 128];   // 32KB: wave-private A-tiles, XOR-swizzled
  __shared__ u16 wbuf[2][128 * 64];   // 32KB: double-buffered weight chunk [n=128][k=64]
  const int et = blockIdx.y;
  const int tid = threadIdx.x;
  const int w = tid >> 6, lane = tid & 63, q = lane >> 4, c = lane & 15;
  const int ebase = blockIdx.x * 128 + w * 32;  // et-local sorted slot base for this wave
  const int win = blockIdx.x * 4 + w;
  const int* __restrict__ src = ssrc + et * NE;
  const int* __restrict__ dst = sdst + et * NE;
  u16* __restrict__ msgs = (et == 0) ? m0 : m1;
  u16* ab = abuf[w];

  // per-lane src row for DMA staging (only lanes 0..31 consumed via shfl)
  int eS = ebase + lane;
  if (eS >= NE) eS = NE - 1;
  const int srow = src[eS];

  int rowD[2];
  #pragma unroll
  for (int mt = 0; mt < 2; ++mt) {
    int e = ebase + mt * 16 + c;
    if (e >= NE) e = NE - 1;
    rowD[mt] = dst[e];
  }

  // issue 8 zero-register DMA gathers: h[src] rows (32) -> own swizzled LDS tile.
  // position (row r, group cg) holds natural group cg ^ (r&15).
  #pragma unroll
  for (int i = 0; i < 8; ++i) {
    const int r = i * 4 + (lane >> 4);  // 0..31
    const int grow = __shfl(srow, r);
    const int cg = lane & 15;
    gload_lds16(h + (size_t)grow * 128 + ((cg ^ (r & 15)) << 3), ab + i * 512);
  }
  // chunk 0 (W0 t=2) into wbuf[0]; nobody reads wbuf before the prologue barrier
  stage_w(W0b + (et * 4 + 2) * 8192, wbuf[0], w, lane);

  // run structure (wave-uniform masks). Cross-lane ops unconditional. Lanes 32..63 are
  // dummies for the 32-edge window: dval=-1 there; scan only reads bits 0..31.
  const int eL = ebase + lane;
  const int dval = (lane < 32 && eL < NE) ? dst[eL] : -1;
  int rpS = 0, rpE = 0;
  if (dval >= 0) {
    rpS = S[et * CELLS + dval] - et * NE;
    rpE = S[et * CELLS + dval + 1] - et * NE;
  }
  const int dlagged = __shfl_up(dval, 1);          // all 64 lanes active
  const bool headp = (lane == 0) | (dval != dlagged);
  const unsigned long long tails = (__ballot(headp) >> 1) | (1ull << 31);
  const unsigned long long intmask = __ballot(dval >= 0 && rpS >= ebase && rpE <= ebase + 32);

  const f32x4 zf = {0.f, 0.f, 0.f, 0.f};
  f32x4 acc[2][8];
  #pragma unroll
  for (int mt = 0; mt < 2; ++mt)
    #pragma unroll
    for (int nt = 0; nt < 8; ++nt) acc[mt][nt] = zf;

  asm volatile("s_waitcnt vmcnt(0)" ::: "memory");  // A-DMAs + chunk 0 landed
  __syncthreads();

  // ---- 10-chunk pipelined K-loop ----
  #pragma unroll 1
  for (int i = 0; i < 10; ++i) {
    // stage next chunk into the buffer whose readers finished at the previous barrier
    if (i < 9) {
      const int j = i + 1;
      const u16* wsrc;
      if (j < 4) {
        const int t = (j < 2) ? (j + 2) : (j - 2);
        wsrc = W0b + (et * 4 + t) * 8192;
      } else {
        const int li = j - 4;  // (l-1)*2 + hh
        wsrc = W123b + (li >> 1) * 32768 + et * 16384 + (li & 1) * 8192;
      }
      stage_w(wsrc, wbuf[j & 1], w, lane);
    }
    // at the start of each layer chunk-pair: flush previous layer into own A-tile
    if (i >= 4 && !(i & 1)) {
      bias_relu_store(acc, bp + ((i - 4) >> 1) * 256 + et * 128, ab, q, c);
      #pragma unroll
      for (int mt = 0; mt < 2; ++mt)
        #pragma unroll
        for (int nt = 0; nt < 8; ++nt) acc[mt][nt] = zf;
    }
    const u16* wb = wbuf[i & 1];
    #pragma unroll
    for (int ks = 0; ks < 2; ++ks) {
      short8 a[2], b[8];
      if (i < 2) {  // dst half of L0: register gathers (sorted runs -> cache hits)
        const int kqh = i * 64 + ks * 32 + q * 8;
        #pragma unroll
        for (int mt = 0; mt < 2; ++mt)
          a[mt] = *(const short8*)(h + (size_t)rowD[mt] * HID + kqh);
      } else {      // src half of L0 / layers 1-3: own swizzled A-tile
        const int blk = (i & 1) * 8 + ks * 4 + q;
        #pragma unroll
        for (int mt = 0; mt < 2; ++mt) {
          const int row = mt * 16 + c;
          a[mt] = *(const short8*)(ab + row * 128 + ((blk ^ c) << 3));
        }
      }
      #pragma unroll
      for (int nt = 0; nt < 8; ++nt)
        b[nt] = *(const short8*)(wb + (nt * 16 + c) * 64 + (((ks * 4 + q) ^ (c & 7)) << 3));
      #pragma unroll
      for (int mt = 0; mt < 2; ++mt)
        #pragma unroll
        for (int nt = 0; nt < 8; ++nt)
          acc[mt][nt] = __builtin_amdgcn_mfma_f32_16x16x32_bf16(a[mt], b[nt], acc[mt][nt], 0, 0, 0);
    }
    // next chunk's DMA latency was covered by this compute; pay only the residual
    asm volatile("s_waitcnt vmcnt(0)" ::: "memory");
    __syncthreads();
  }

  // layer-3 epilogue: +bias into fp32 fab (two 64-feature passes), column scan over the
  // 32 edges; interior flush = 128B coalesced bf16 store; boundary flush = fp32 partial.
  float bias[8];
  #pragma unroll
  for (int j = 0; j < 8; ++j) bias[j] = bp[3 * 256 + et * 128 + c * 8 + j];

  float* fab = (float*)ab;  // 32 rows x 64 feature-slots fp32 (8KB, wave-private)
  #pragma unroll
  for (int half = 0; half < 2; ++half) {
    #pragma unroll
    for (int mt = 0; mt < 2; ++mt) {
      #pragma unroll
      for (int r = 0; r < 4; ++r) {
        const int row = mt * 16 + 4 * q + r;
        f32x4 t;
        #pragma unroll
        for (int nti = 0; nti < 4; ++nti)
          t[nti] = acc[mt][half * 4 + nti][r] + bias[half * 4 + nti];
        *(f32x4*)(fab + row * 64 + c * 4) = t;
      }
    }
    float run = 0.f;
    int jstart = 0;
    #pragma unroll 1
    for (int jb = 0; jb < 32; jb += 8) {
      #pragma unroll
      for (int u = 0; u < 8; ++u) {
        const int j = jb + u;
        run += fab[j * 64 + lane];
        if ((tails >> j) & 1) {  // wave-uniform flush at run tail
          const int d = __builtin_amdgcn_readlane(dval, j);
          if (d >= 0) {
            if ((intmask >> j) & 1) {
              msgs[(size_t)d * HID + half * 64 + lane] = f2bf(run);
            } else {
              const int slot = (jstart == 0) ? 0 : 1;  // only first/last runs can straddle
              const size_t sb = ((size_t)et * NWIN + win) * 2 + slot;
              side_part[sb * 128 + half * 64 + lane] = run;
              if (lane == 0 && half == 0) side_dst[sb] = d;
            }
          }
          run = 0.f;
          jstart = j + 1;
        }
      }
    }
  }
}

// ---------------- boundary fixup: owner window sums fp32 partials, writes bf16 m ------
// 32-edge windows: owner = r0>>5.
__global__ void fixup_kernel(const int* __restrict__ S,
                             const int* __restrict__ side_dst,
                             const float* __restrict__ side_part,
                             u16* __restrict__ m0, u16* __restrict__ m1)
{
  const int b = blockIdx.x;           // et*NWIN + win
  const int et = b / NWIN, win = b - et * NWIN;
  const int t = threadIdx.x;          // 0..127
  u16* __restrict__ m = et ? m1 : m0;
  #pragma unroll
  for (int s = 0; s < 2; ++s) {
    const int d = side_dst[b * 2 + s];
    if (d < 0) continue;
    const int r0 = S[et * CELLS + d] - et * NE;
    if ((r0 >> 5) != win) continue;   // not the owner window (32-edge windows)
    const int w1 = (S[et * CELLS + d + 1] - et * NE - 1) >> 5;
    float sum = 0.f;
    for (int wi = win; wi <= w1; ++wi) {
      const int base = (et * NWIN + wi) * 2;
      if (side_dst[base + 0] == d) sum += side_part[(size_t)(base + 0) * 128 + t];
      if (side_dst[base + 1] == d) sum += side_part[(size_t)(base + 1) * 128 + t];
    }
    m[(size_t)d * HID + t] = f2bf(sum);
  }
}

// ---------------- fused LSTM: gates GEMM (K=512) + in-register activations + score -------
// block: 8 waves, 64 cells. Wave wf owns feature cols [wf*16, wf*16+16) for ALL 4 gates.
// rc is bf16; step 0 skips the rc read (known zero); final step skips rc/h writes.
__launch_bounds__(512, 4)
__global__ void lstm_kernel(
    const int step,
    const u16* __restrict__ xb, const u16* __restrict__ mm0, const u16* __restrict__ mm1,
    u16* __restrict__ h, u16* __restrict__ rc,
    const u16* __restrict__ Wcb, const float* __restrict__ swp,
    float* __restrict__ out)
{
  __shared__ u16 at[64 * 512];  // 64KB: A-tile, later reused for score partials
  const int tid = threadIdx.x;
  const int cb = blockIdx.x * 64;

  // stage A = [x | m0 | m1 | rh] bf16; m already bf16 in storage order (Wcb K matches)
  for (int base = tid * 8; base < 64 * 512; base += 4096) {
    const int cl = base >> 9, s = base & 511;
    const int cell = cb + cl;
    short8 t;
    if (s < 128) {
      t = *(const short8*)(xb + cell * 128 + s);
    } else if (s < 384) {
      const u16* mp = (s < 256 ? mm0 : mm1) + cell * 128 + (s & 127);
      t = *(const short8*)(mp);
    } else if (step == 0) {
      #pragma unroll
      for (int j = 0; j < 8; ++j) t[j] = 0;
    } else {
      t = *(const short8*)(h + cell * 128 + (s & 127));
    }
    const int blk = s >> 3;
    const int blks = (blk & 48) | ((blk ^ cl) & 15);
    *(short8*)(at + cl * 512 + blks * 8) = t;
  }
  __syncthreads();

  const int w = tid >> 6, lane = tid & 63, q = lane >> 4, c = lane & 15;
  const int wf = w;  // feature-16 group
  const f32x4 zf = {0.f, 0.f, 0.f, 0.f};
  f32x4 acc[4][4];  // [cell-tile][gate]
  #pragma unroll
  for (int mt = 0; mt < 4; ++mt)
    #pragma unroll
    for (int g = 0; g < 4; ++g) acc[mt][g] = zf;

  #pragma unroll
  for (int ks = 0; ks < 16; ++ks) {
    const int kq = ks * 32 + q * 8;
    const int blk = kq >> 3;
    short8 a[4], b[4];
    #pragma unroll
    for (int mt = 0; mt < 4; ++mt) {
      const int row = mt * 16 + c;
      const int blks = (blk & 48) | ((blk ^ c) & 15);
      a[mt] = *(const short8*)(at + row * 512 + blks * 8);
    }
    #pragma unroll
    for (int g = 0; g < 4; ++g)
      b[g] = *(const short8*)(Wcb + (g * 128 + wf * 16 + c) * 512 + kq);
    #pragma unroll
    for (int mt = 0; mt < 4; ++mt)
      #pragma unroll
      for (int g = 0; g < 4; ++g)
        acc[mt][g] = __builtin_amdgcn_mfma_f32_16x16x32_bf16(a[mt], b[g], acc[mt][g], 0, 0, 0);
  }
  __syncthreads();  // tile reads done everywhere; safe to reuse for score partials

  // in-register LSTM epilogue: lane (q,c) per (mt,r): cell = mt*16+4q+r, feat = wf*16+c
  const float swc = swp[wf * 16 + c];
  const bool last = (step == NSTEPS - 1);
  float* pt = (float*)at;  // [8 waves][64 cells] score partials
  #pragma unroll
  for (int mt = 0; mt < 4; ++mt) {
    #pragma unroll
    for (int r = 0; r < 4; ++r) {
      const int cl = mt * 16 + 4 * q + r;
      const int cell = cb + cl;
      const float ig = sigm(acc[mt][0][r]);
      const float fg = sigm(acc[mt][1][r]);
      const float gg = tanha(acc[mt][2][r]);
      const float og = sigm(acc[mt][3][r]);
      u16* rcp = rc + (size_t)cell * HID + wf * 16 + c;
      const float c0 = (step == 0) ? 0.f : bf2f(rcp[0]);
      const float nc = fg * c0 + ig * gg;
      const float nhv = og * tanha(nc);
      if (!last) {
        rcp[0] = f2bf(nc);
        h[(size_t)cell * HID + wf * 16 + c] = f2bf(nhv);
      }
      float v = nhv * swc;  // score partial, reduce over c (16 feats)
      v += __shfl_xor(v, 1); v += __shfl_xor(v, 2);
      v += __shfl_xor(v, 4); v += __shfl_xor(v, 8);
      if (c == 0) pt[wf * 64 + cl] = v;
    }
  }
  __syncthreads();
  if (tid < 64) {
    float s = 0.f;
    #pragma unroll
    for (int ww = 0; ww < 8; ++ww) s += pt[ww * 64 + tid];
    out[step * CELLS + cb + tid] = s;
  }
}

extern "C" void kernel_launch(void* const* d_in, const int* in_sizes, int n_in,
                              void* d_out, int out_size, void* d_ws, size_t ws_size,
                              hipStream_t stream)
{
  const int* q      = (const int*)d_in[0];
  const int* esrc   = (const int*)d_in[1];
  const int* edst   = (const int*)d_in[2];
  const float* embed= (const float*)d_in[3];
  const float* W0   = (const float*)d_in[4];
  const float* b0   = (const float*)d_in[5];
  const float* W1   = (const float*)d_in[6];
  const float* b1   = (const float*)d_in[7];
  const float* W2   = (const float*)d_in[8];
  const float* b2   = (const float*)d_in[9];
  const float* W3   = (const float*)d_in[10];
  const float* b3   = (const float*)d_in[11];
  const float* Wih  = (const float*)d_in[12];
  const float* Whh  = (const float*)d_in[13];
  const float* sw   = (const float*)d_in[14];

  char* ws = (char*)d_ws;
  size_t off = 0;
  auto alloc = [&](size_t bytes) {
    void* p = ws + off;
    off += (bytes + 255) & ~(size_t)255;
    return p;
  };
  u16*   h    = (u16*)  alloc((size_t)CELLS * HID * 2);
  u16*   xb   = (u16*)  alloc((size_t)CELLS * HID * 2);
  u16*   rc   = (u16*)  alloc((size_t)CELLS * HID * 2);  // bf16 carry
  u16*   m0   = (u16*)  alloc((size_t)CELLS * HID * 2);  // bf16; m1 contiguous after
  u16*   m1   = (u16*)  alloc((size_t)CELLS * HID * 2);
  u16*   W0b  = (u16*)  alloc(2 * 128 * 256 * 2);
  u16*   W123b= (u16*)  alloc((size_t)3 * 2 * 128 * 128 * 2);  // layers 1..3 contiguous
  u16*   Wcb  = (u16*)  alloc(512 * 512 * 2);
  float* bp   = (float*)alloc(4 * 256 * 4);
  u16*   embp = (u16*)  alloc(384 * 2);
  float* swp  = (float*)alloc(128 * 4);
  // sort workspace
  int*   counts = (int*)alloc((size_t)2 * CELLS * 4);
  int*   Sarr   = (int*)alloc(((size_t)2 * CELLS + 1) * 4);
  int*   fill   = (int*)alloc((size_t)2 * CELLS * 4);
  int*   btot   = (int*)alloc(192 * 4);
  int*   boffs  = (int*)alloc(192 * 4);
  int*   ssrc   = (int*)alloc((size_t)2 * NE * 4);
  int*   sdst   = (int*)alloc((size_t)2 * NE * 4);
  // boundary side buffers (32-edge windows: 2*NWIN*2 slots)
  int*   side_dst  = (int*)  alloc((size_t)2 * NWIN * 2 * 4);
  float* side_part = (float*)alloc((size_t)2 * NWIN * 2 * 128 * 4);

  prep_kernel<<<1670, 256, 0, stream>>>(W0, W1, W2, W3, b0, b1, b2, b3, Wih, Whh, embed, sw,
                                        W0b, W123b, Wcb, bp, embp, swp);
  init_kernel<<<(CELLS * HID) / 256, 256, 0, stream>>>(q, embp, xb, h);

  // dst-sort both edge types
  hipMemsetAsync(counts, 0, (size_t)2 * CELLS * 4, stream);
  hipMemsetAsync(fill, 0, (size_t)2 * CELLS * 4, stream);
  hist_kernel<<<(2 * NE + 255) / 256, 256, 0, stream>>>(edst, counts);
  scan1_kernel<<<192, 1024, 0, stream>>>(counts, Sarr, btot);
  scan2_kernel<<<1, 256, 0, stream>>>(btot, boffs, Sarr);
  scan3_kernel<<<192, 1024, 0, stream>>>(Sarr, boffs);
  scatter_kernel<<<(2 * NE + 255) / 256, 256, 0, stream>>>(esrc, edst, Sarr, fill, ssrc, sdst);

  // m zeroing hoisted out of the step loop: every dst with >=1 edge gets its full row
  // rewritten each step (interior flush or fixup); zero-degree rows stay zero. side_dst
  // values are step-invariant (same sorted graph), so one 0xFF fill suffices.
  hipMemsetAsync(m0, 0, (size_t)2 * CELLS * HID * 2, stream);        // m0+m1 (bf16)
  hipMemsetAsync(side_dst, 0xFF, (size_t)2 * NWIN * 2 * 4, stream);  // dst = -1

  for (int step = 0; step < NSTEPS; ++step) {
    msg_kernel<<<dim3((NE + 127) / 128, 2), 256, 0, stream>>>(h, ssrc, sdst, Sarr,
                                                              W0b, W123b, bp,
                                                              m0, m1, side_dst, side_part);
    fixup_kernel<<<2 * NWIN, 128, 0, stream>>>(Sarr, side_dst, side_part, m0, m1);
    lstm_kernel<<<CELLS / 64, 512, 0, stream>>>(step, xb, m0, m1, h, rc, Wcb, swp, (float*)d_out);
  }
}

// Round 9
// 702.176 us; speedup vs baseline: 1.0948x; 1.0321x over previous
//
#include <hip/hip_runtime.h>

#define HID 128
#define CELLS 98304
#define NE 250000
#define NSTEPS 2
#define NWIN 3912  // 64-edge windows per edge type = 489 blocks * 8 waves

typedef __attribute__((ext_vector_type(8))) short short8;
typedef __attribute__((ext_vector_type(4))) float f32x4;
typedef __attribute__((ext_vector_type(4))) unsigned int u32x4;
typedef unsigned short u16;

// pi permutation: pi-slot s <-> natural col permf(s)
__device__ __forceinline__ int permf(int s) { return ((s & 7) << 4) | (s >> 3); }
// m storage position p: half = p>>6, lane = p&63,
// pi-slot = (lane>>2)*8 + half*4 + (lane&3); natural col = permf(slot)
__device__ __forceinline__ int nat_of_pos(int p) {
  int l = p & 63, hf = p >> 6;
  int slot = ((l >> 2) << 3) + (hf << 2) + (l & 3);
  return ((slot & 7) << 4) | (slot >> 3);
}

__device__ __forceinline__ u16 f2bf(float f) {
  unsigned int u = __builtin_bit_cast(unsigned int, f);
  u += 0x7fffu + ((u >> 16) & 1u);
  return (u16)(u >> 16);
}
__device__ __forceinline__ float bf2f(u16 s) {
  unsigned int u = ((unsigned int)s) << 16;
  return __builtin_bit_cast(float, u);
}
// packed f32x2 -> bf16x2 (RNE), lo -> D[15:0], hi -> D[31:16]
__device__ __forceinline__ unsigned int cvtpk_bf16(float lo, float hi) {
  unsigned int r;
  asm("v_cvt_pk_bf16_f32 %0, %1, %2" : "=v"(r) : "v"(lo), "v"(hi));
  return r;
}
__device__ __forceinline__ float sigm(float x) { return 1.f / (1.f + __expf(-x)); }
__device__ __forceinline__ float tanha(float x) { return 1.f - 2.f / (__expf(2.f * x) + 1.f); }

// zero-register DMA: 16B per lane, global(per-lane addr) -> LDS (wave-uniform base + lane*16)
__device__ __forceinline__ void gload_lds16(const u16* g, u16* l) {
  __builtin_amdgcn_global_load_lds(
      (const __attribute__((address_space(1))) unsigned int*)(const void*)g,
      (__attribute__((address_space(3))) unsigned int*)(void*)l, 16, 0, 0);
}

// cooperative 16KB weight-chunk stage (msg): 512 threads x 2 insts x 16B, linear
__device__ __forceinline__ void stage_w(const u16* __restrict__ ws, u16* wl, int w, int lane) {
  #pragma unroll
  for (int i = 0; i < 2; ++i)
    gload_lds16(ws + i * 4096 + w * 512 + lane * 8, wl + i * 4096 + w * 512);
}

// ---------------- prep: bf16-convert weights ----------------
// W0b: [et][chunk t=0..3][n=128][s=64] -- K-chunks of 64, XOR-swizzled within chunk:
//   position group g' (0..7) of row n holds natural k-group g'^(n&7) of chunk t.
//   t=0,1: src half (k 0..127), t=2,3: dst half (k 128..255). Natural K (h order).
// W123b: [l-1][et][half hh][n][s=64], same per-chunk swizzle, K pi-permuted (tile order).
// Wcb2 (R9): [kc=0..7][n=0..511][g'=0..7][j=0..7] -- lstm gates weights in K-chunks of
//   64, XOR-swizzled within chunk (position g' of row n holds natural chunk-group
//   g'^(n&7)); K semantics: [Wih(x | m0 | m1) | Whh] with m-blocks in m-storage order.
__global__ void prep_kernel(
    const float* __restrict__ W0, const float* __restrict__ W1,
    const float* __restrict__ W2, const float* __restrict__ W3,
    const float* __restrict__ b0, const float* __restrict__ b1,
    const float* __restrict__ b2, const float* __restrict__ b3,
    const float* __restrict__ Wih, const float* __restrict__ Whh,
    const float* __restrict__ embed, const float* __restrict__ sw,
    u16* __restrict__ W0b, u16* __restrict__ W123b,
    u16* __restrict__ Wcb, float* __restrict__ bp,
    u16* __restrict__ embp, float* __restrict__ swp)
{
  int idx = blockIdx.x * 256 + threadIdx.x;
  if (idx < 65536) {  // W0b swizzled chunks
    int et = idx >> 15, t = (idx >> 13) & 3, n = (idx >> 6) & 127, s = idx & 63;
    int g = s >> 3, j = s & 7;
    int gn = g ^ (n & 7);
    W0b[idx] = f2bf(W0[(et * 128 + n) * 256 + t * 64 + gn * 8 + j]);
    return;
  }
  idx -= 65536;
  if (idx < 98304) {  // W123b swizzled half-chunks, K pi-permuted
    int which = idx >> 15, r = idx & 32767;
    int et = r >> 14, hh = (r >> 13) & 1, n = (r >> 6) & 127, s = r & 63;
    int g = s >> 3, j = s & 7;
    int gn = g ^ (n & 7);
    const float* W = which == 0 ? W1 : (which == 1 ? W2 : W3);
    W123b[which * 32768 + r] = f2bf(W[(et * 128 + n) * 128 + permf(hh * 64 + gn * 8 + j)]);
    return;
  }
  idx -= 98304;
  if (idx < 262144) {  // Wcb2 chunk-swizzled lstm weights
    int kc = idx >> 15, r = idx & 32767;
    int n = r >> 6, s = r & 63;
    int gp = s >> 3, j = s & 7;
    int k = kc * 64 + ((gp ^ (n & 7)) << 3) + j;   // natural concat-K position
    int blk = k >> 7, s7 = k & 127;
    int k7 = (blk == 1 || blk == 2) ? nat_of_pos(s7) : s7;  // x / rh natural
    float v = (blk < 3) ? Wih[n * 384 + blk * 128 + k7] : Whh[n * 128 + k7];
    Wcb[idx] = f2bf(v);
    return;
  }
  idx -= 262144;
  if (idx < 1024) {  // biases [layer 0..3][et][slot] pi-order
    int l = idx >> 8, r = idx & 255;
    int et = r >> 7, s = r & 127;
    const float* b = l == 0 ? b0 : (l == 1 ? b1 : (l == 2 ? b2 : b3));
    bp[idx] = b[et * 128 + permf(s)];
    return;
  }
  idx -= 1024;
  if (idx < 384) {  // embed natural bf16
    embp[idx] = f2bf(embed[idx]);
    return;
  }
  idx -= 384;
  if (idx < 128) swp[idx] = sw[idx];
}

// ---------------- init: x = embed[q] (natural, bf16), h = x (rc untouched:
// step 0 never reads it) ----------------
__global__ void init_kernel(const int* __restrict__ q, const u16* __restrict__ embp,
                            u16* __restrict__ xb, u16* __restrict__ h)
{
  int idx = blockIdx.x * 256 + threadIdx.x;
  int c = idx >> 7, s = idx & 127;
  u16 v = embp[q[c] * 128 + s];
  xb[idx] = v;
  h[idx] = v;
}

// ---------------- dst-sort pipeline: hist -> scan (2-level) -> scatter ----------------
__global__ void hist_kernel(const int* __restrict__ edst, int* __restrict__ counts)
{
  int idx = blockIdx.x * 256 + threadIdx.x;
  if (idx >= 2 * NE) return;
  int et = (idx >= NE) ? 1 : 0;
  atomicAdd(&counts[et * CELLS + edst[idx]], 1);
}

__global__ void scan1_kernel(const int* __restrict__ counts, int* __restrict__ S,
                             int* __restrict__ btot)
{
  __shared__ int sh[1024];
  const int t = threadIdx.x, b = blockIdx.x;
  const int i = b * 1024 + t;
  int v = counts[i];
  sh[t] = v;
  __syncthreads();
  int acc = v;
  for (int off = 1; off < 1024; off <<= 1) {
    int add = (t >= off) ? sh[t - off] : 0;
    __syncthreads();
    acc += add;
    sh[t] = acc;
    __syncthreads();
  }
  S[i] = acc - v;  // block-local exclusive
  if (t == 1023) btot[b] = acc;
}

__global__ void scan2_kernel(const int* __restrict__ btot, int* __restrict__ boffs,
                             int* __restrict__ S)
{
  __shared__ int sh[256];
  const int t = threadIdx.x;
  int v = (t < 192) ? btot[t] : 0;
  sh[t] = v;
  __syncthreads();
  int acc = v;
  for (int off = 1; off < 256; off <<= 1) {
    int add = (t >= off) ? sh[t - off] : 0;
    __syncthreads();
    acc += add;
    sh[t] = acc;
    __syncthreads();
  }
  if (t < 192) boffs[t] = acc - v;
  if (t == 0) S[2 * CELLS] = 2 * NE;
}

__global__ void scan3_kernel(int* __restrict__ S, const int* __restrict__ boffs)
{
  const int i = blockIdx.x * 1024 + threadIdx.x;
  S[i] += boffs[blockIdx.x];
}

__global__ void scatter_kernel(const int* __restrict__ esrc, const int* __restrict__ edst,
                               const int* __restrict__ S, int* __restrict__ fill,
                               int* __restrict__ ssrc, int* __restrict__ sdst)
{
  int idx = blockIdx.x * 256 + threadIdx.x;
  if (idx >= 2 * NE) return;
  int et = (idx >= NE) ? 1 : 0;
  int d = edst[idx];
  int pos = atomicAdd(&fill[et * CELLS + d], 1);
  int slot = S[et * CELLS + d] - et * NE + pos;  // et-local sorted slot
  sdst[et * NE + slot] = d;
  ssrc[et * NE + slot] = esrc[idx];
}

// bias + relu + pack-transpose into swizzled per-wave LDS A-tile (pitch 128, 8-col XOR
// swizzle). Packed conversion via cvt_pk (R6).
__device__ __forceinline__ void bias_relu_store(f32x4 (&acc)[4][8], const float* __restrict__ bl,
                                                u16* __restrict__ ab, int q, int c)
{
  float bias[8];
  #pragma unroll
  for (int j = 0; j < 8; ++j) bias[j] = bl[c * 8 + j];
  #pragma unroll
  for (int mt = 0; mt < 4; ++mt) {
    #pragma unroll
    for (int r = 0; r < 4; ++r) {
      const int rowl = mt * 16 + 4 * q + r;
      u32x4 t;
      #pragma unroll
      for (int p = 0; p < 4; ++p) {
        float v0 = acc[mt][2 * p][r] + bias[2 * p];
        float v1 = acc[mt][2 * p + 1][r] + bias[2 * p + 1];
        v0 = v0 > 0.f ? v0 : 0.f;
        v1 = v1 > 0.f ? v1 : 0.f;
        t[p] = cvtpk_bf16(v0, v1);
      }
      *(u32x4*)(ab + rowl * 128 + ((c ^ (rowl & 15)) << 3)) = t;
    }
  }
}

// ---------------- fused 4-layer edge MLP + sorted segmented-sum scatter ----------------
// R8 post-mortem: 2 barrier domains/CU NEUTRAL on msg and +14us of fixup overhead ->
// REVERTED to the measured-best R6 config (8-wave blocks, 64-edge windows, 10-chunk
// 2-deep wbuf pipeline, cvt_pk packing). msg is parked at ~160us (~5x MFMA floor);
// R9 attacks the lstm instead.
__launch_bounds__(512, 2)
__global__ void msg_kernel(
    const u16* __restrict__ h,
    const int* __restrict__ ssrc, const int* __restrict__ sdst,
    const int* __restrict__ S,
    const u16* __restrict__ W0b, const u16* __restrict__ W123b,
    const float* __restrict__ bp,
    u16* __restrict__ m0, u16* __restrict__ m1,
    int* __restrict__ side_dst, float* __restrict__ side_part)
{
  __shared__ u16 abuf[8][64 * 128];   // 128KB: wave-private A-tiles, XOR-swizzled
  __shared__ u16 wbuf[2][128 * 64];   // 32KB: double-buffered weight chunk [n=128][k=64]
  const int et = blockIdx.y;
  const int tid = threadIdx.x;
  const int w = tid >> 6, lane = tid & 63, q = lane >> 4, c = lane & 15;
  const int ebase = blockIdx.x * 512 + w * 64;  // et-local sorted slot base for this wave
  const int win = blockIdx.x * 8 + w;
  const int* __restrict__ src = ssrc + et * NE;
  const int* __restrict__ dst = sdst + et * NE;
  u16* __restrict__ msgs = (et == 0) ? m0 : m1;
  u16* ab = abuf[w];

  // per-lane src row for DMA staging; per-lane dst rows for register gathers
  int eS = ebase + lane;
  if (eS >= NE) eS = NE - 1;
  const int srow = src[eS];

  int rowD[4];
  #pragma unroll
  for (int mt = 0; mt < 4; ++mt) {
    int e = ebase + mt * 16 + c;
    if (e >= NE) e = NE - 1;
    rowD[mt] = dst[e];
  }

  // issue 16 zero-register DMA gathers: h[src] rows -> own swizzled LDS tile.
  // position (row r, group cg) holds natural group cg ^ (r&15).
  #pragma unroll
  for (int i = 0; i < 16; ++i) {
    const int r = i * 4 + (lane >> 4);
    const int grow = __shfl(srow, r);
    const int cg = lane & 15;
    gload_lds16(h + (size_t)grow * 128 + ((cg ^ (r & 15)) << 3), ab + i * 512);
  }
  // chunk 0 (W0 t=2) into wbuf[0]; nobody reads wbuf before the prologue barrier
  stage_w(W0b + (et * 4 + 2) * 8192, wbuf[0], w, lane);

  // run structure (wave-uniform masks). Cross-lane ops unconditional.
  const int eL = ebase + lane;
  const int dval = (eL < NE) ? dst[eL] : -1;
  int rpS = 0, rpE = 0;
  if (dval >= 0) {
    rpS = S[et * CELLS + dval] - et * NE;
    rpE = S[et * CELLS + dval + 1] - et * NE;
  }
  const int dlagged = __shfl_up(dval, 1);          // all 64 lanes active
  const bool headp = (lane == 0) | (dval != dlagged);
  const unsigned long long tails = (__ballot(headp) >> 1) | (1ull << 63);
  const unsigned long long intmask = __ballot(dval >= 0 && rpS >= ebase && rpE <= ebase + 64);

  const f32x4 zf = {0.f, 0.f, 0.f, 0.f};
  f32x4 acc[4][8];
  #pragma unroll
  for (int mt = 0; mt < 4; ++mt)
    #pragma unroll
    for (int nt = 0; nt < 8; ++nt) acc[mt][nt] = zf;

  asm volatile("s_waitcnt vmcnt(0)" ::: "memory");  // A-DMAs + chunk 0 landed
  __syncthreads();

  // ---- 10-chunk pipelined K-loop ----
  #pragma unroll 1
  for (int i = 0; i < 10; ++i) {
    // stage next chunk into the buffer whose readers finished at the previous barrier
    if (i < 9) {
      const int j = i + 1;
      const u16* wsrc;
      if (j < 4) {
        const int t = (j < 2) ? (j + 2) : (j - 2);
        wsrc = W0b + (et * 4 + t) * 8192;
      } else {
        const int li = j - 4;  // (l-1)*2 + hh
        wsrc = W123b + (li >> 1) * 32768 + et * 16384 + (li & 1) * 8192;
      }
      stage_w(wsrc, wbuf[j & 1], w, lane);
    }
    // at the start of each layer chunk-pair: flush previous layer into own A-tile
    if (i >= 4 && !(i & 1)) {
      bias_relu_store(acc, bp + ((i - 4) >> 1) * 256 + et * 128, ab, q, c);
      #pragma unroll
      for (int mt = 0; mt < 4; ++mt)
        #pragma unroll
        for (int nt = 0; nt < 8; ++nt) acc[mt][nt] = zf;
    }
    const u16* wb = wbuf[i & 1];
    #pragma unroll
    for (int ks = 0; ks < 2; ++ks) {
      short8 a[4], b[8];
      if (i < 2) {  // dst half of L0: register gathers (sorted runs -> cache hits)
        const int kqh = i * 64 + ks * 32 + q * 8;
        #pragma unroll
        for (int mt = 0; mt < 4; ++mt)
          a[mt] = *(const short8*)(h + (size_t)rowD[mt] * HID + kqh);
      } else {      // src half of L0 / layers 1-3: own swizzled A-tile
        const int blk = (i & 1) * 8 + ks * 4 + q;
        #pragma unroll
        for (int mt = 0; mt < 4; ++mt) {
          const int row = mt * 16 + c;
          a[mt] = *(const short8*)(ab + row * 128 + ((blk ^ c) << 3));
        }
      }
      #pragma unroll
      for (int nt = 0; nt < 8; ++nt)
        b[nt] = *(const short8*)(wb + (nt * 16 + c) * 64 + (((ks * 4 + q) ^ (c & 7)) << 3));
      #pragma unroll
      for (int mt = 0; mt < 4; ++mt)
        #pragma unroll
        for (int nt = 0; nt < 8; ++nt)
          acc[mt][nt] = __builtin_amdgcn_mfma_f32_16x16x32_bf16(a[mt], b[nt], acc[mt][nt], 0, 0, 0);
    }
    // next chunk's DMA latency was covered by this compute; pay only the residual
    asm volatile("s_waitcnt vmcnt(0)" ::: "memory");
    __syncthreads();
  }

  // layer-3 epilogue: +bias into fp32 fab (two 64-feature passes), column scan; interior
  // flush = 128B coalesced bf16 store; boundary flush = fp32 partial to side buffer.
  float bias[8];
  #pragma unroll
  for (int j = 0; j < 8; ++j) bias[j] = bp[3 * 256 + et * 128 + c * 8 + j];

  float* fab = (float*)ab;  // 64 rows x 64 feature-slots fp32 (16KB, wave-private)
  #pragma unroll
  for (int half = 0; half < 2; ++half) {
    #pragma unroll
    for (int mt = 0; mt < 4; ++mt) {
      #pragma unroll
      for (int r = 0; r < 4; ++r) {
        const int row = mt * 16 + 4 * q + r;
        f32x4 t;
        #pragma unroll
        for (int nti = 0; nti < 4; ++nti)
          t[nti] = acc[mt][half * 4 + nti][r] + bias[half * 4 + nti];
        *(f32x4*)(fab + row * 64 + c * 4) = t;
      }
    }
    float run = 0.f;
    int jstart = 0;
    #pragma unroll 1
    for (int jb = 0; jb < 64; jb += 8) {
      #pragma unroll
      for (int u = 0; u < 8; ++u) {
        const int j = jb + u;
        run += fab[j * 64 + lane];
        if ((tails >> j) & 1) {  // wave-uniform flush at run tail
          const int d = __builtin_amdgcn_readlane(dval, j);
          if (d >= 0) {
            if ((intmask >> j) & 1) {
              msgs[(size_t)d * HID + half * 64 + lane] = f2bf(run);
            } else {
              const int slot = (jstart == 0) ? 0 : 1;  // only first/last runs can straddle
              const size_t sb = ((size_t)et * NWIN + win) * 2 + slot;
              side_part[sb * 128 + half * 64 + lane] = run;
              if (lane == 0 && half == 0) side_dst[sb] = d;
            }
          }
          run = 0.f;
          jstart = j + 1;
        }
      }
    }
  }
}

// ---------------- boundary fixup: owner window sums fp32 partials, writes bf16 m ------
__global__ void fixup_kernel(const int* __restrict__ S,
                             const int* __restrict__ side_dst,
                             const float* __restrict__ side_part,
                             u16* __restrict__ m0, u16* __restrict__ m1)
{
  const int b = blockIdx.x;           // et*NWIN + win
  const int et = b / NWIN, win = b - et * NWIN;
  const int t = threadIdx.x;          // 0..127
  u16* __restrict__ m = et ? m1 : m0;
  #pragma unroll
  for (int s = 0; s < 2; ++s) {
    const int d = side_dst[b * 2 + s];
    if (d < 0) continue;
    const int r0 = S[et * CELLS + d] - et * NE;
    if ((r0 >> 6) != win) continue;   // not the owner window (64-edge windows)
    const int w1 = (S[et * CELLS + d + 1] - et * NE - 1) >> 6;
    float sum = 0.f;
    for (int wi = win; wi <= w1; ++wi) {
      const int base = (et * NWIN + wi) * 2;
      if (side_dst[base + 0] == d) sum += side_part[(size_t)(base + 0) * 128 + t];
      if (side_dst[base + 1] == d) sum += side_part[(size_t)(base + 1) * 128 + t];
    }
    m[(size_t)d * HID + t] = f2bf(sum);
  }
}

// ---------------- fused LSTM: gates GEMM (K=512) + in-register activations + score -------
// R9 REBUILD with the R4/R5-proven medicine: K chunked 8x64; per chunk, cooperatively
// DMA-stage the W-chunk (64KB from pre-swizzled Wcb2) + A-chunk (8KB; each 64-K chunk
// maps cleanly to one source array: kc 0,1->xb, 2,3->m0, 4,5->m1, 6,7->rh(h or zeros))
// via zero-register global_load_lds, double-buffered, ONE vmcnt(0)+barrier per chunk.
// Replaces each thread's serial 4KB L2-stream of Wcb (the latency chain) with bulk DMA
// overlapped under MFMA. LDS 2x64K + 2x8K = 144KB -> 1 block/CU, full reg budget.
// Swizzles replicate msg's measured-zero-conflict pattern (XOR row&7 over 8 groups).
// Mapping/epilogue unchanged: wave wf owns feature cols [wf*16,wf*16+16) for all 4 gates.
__launch_bounds__(512, 2)
__global__ void lstm_kernel(
    const int step,
    const u16* __restrict__ xb, const u16* __restrict__ mm0, const u16* __restrict__ mm1,
    u16* __restrict__ h, u16* __restrict__ rc,
    const u16* __restrict__ Wcb, const float* __restrict__ swp,
    const u16* __restrict__ zrow,
    float* __restrict__ out)
{
  __shared__ u16 wbuf[2][512 * 64];  // 128KB: W K-chunks [n=512][8 grp x 8], swizzled
  __shared__ u16 abuf[2][64 * 64];   // 16KB: A K-chunks [cell=64][8 grp x 8], swizzled
  const int tid = threadIdx.x;
  const int cb = blockIdx.x * 64;
  const int w = tid >> 6, lane = tid & 63, q = lane >> 4, c = lane & 15;

  const f32x4 zf = {0.f, 0.f, 0.f, 0.f};
  f32x4 acc[4][4];  // [cell-tile][gate]
  #pragma unroll
  for (int mt = 0; mt < 4; ++mt)
    #pragma unroll
    for (int g = 0; g < 4; ++g) acc[mt][g] = zf;

  // A-chunk stage: thread t -> LDS slot t*16B = (cell cl=t>>3, group pos lg=t&7);
  // source col within the 128-col source span = (kc&1)*64 + ((lg ^ (cl&7))<<3).
  const int scl = tid >> 3, slg = tid & 7;
  const int scol0 = ((slg ^ (scl & 7)) << 3);
  #define STAGE_A(kc, buf)                                                         \
    {                                                                              \
      const int col = (((kc) & 1) << 6) + scol0;                                   \
      const int sel = (kc) >> 1;                                                   \
      const u16* srcp;                                                             \
      if (sel == 0)      srcp = xb  + (size_t)(cb + scl) * 128 + col;              \
      else if (sel == 1) srcp = mm0 + (size_t)(cb + scl) * 128 + col;              \
      else if (sel == 2) srcp = mm1 + (size_t)(cb + scl) * 128 + col;              \
      else srcp = (step == 0) ? (zrow + col) : (h + (size_t)(cb + scl) * 128 + col); \
      gload_lds16(srcp, abuf[buf] + w * 512);                                      \
    }
  // W-chunk stage: 64KB linear copy from pre-swizzled Wcb2 chunk kc (8 insts/thread)
  #define STAGE_W(kc, buf)                                                         \
    {                                                                              \
      _Pragma("unroll")                                                            \
      for (int i = 0; i < 8; ++i)                                                  \
        gload_lds16(Wcb + (size_t)(kc) * 32768 + i * 4096 + tid * 8,               \
                    wbuf[buf] + i * 4096 + w * 512);                               \
    }

  STAGE_A(0, 0);
  STAGE_W(0, 0);
  asm volatile("s_waitcnt vmcnt(0)" ::: "memory");
  __syncthreads();

  #pragma unroll 1
  for (int kc = 0; kc < 8; ++kc) {
    if (kc < 7) {
      STAGE_A(kc + 1, (kc + 1) & 1);
      STAGE_W(kc + 1, (kc + 1) & 1);
    }
    const u16* ac = abuf[kc & 1];
    const u16* wc = wbuf[kc & 1];
    #pragma unroll
    for (int kk = 0; kk < 2; ++kk) {
      const int lg = kk * 4 + q;
      short8 a[4], b[4];
      #pragma unroll
      for (int mt = 0; mt < 4; ++mt) {
        const int row = mt * 16 + c;
        a[mt] = *(const short8*)(ac + row * 64 + ((lg ^ (row & 7)) << 3));
      }
      #pragma unroll
      for (int g = 0; g < 4; ++g) {
        const int n = g * 128 + w * 16 + c;
        b[g] = *(const short8*)(wc + n * 64 + ((lg ^ (n & 7)) << 3));
      }
      #pragma unroll
      for (int mt = 0; mt < 4; ++mt)
        #pragma unroll
        for (int g = 0; g < 4; ++g)
          acc[mt][g] = __builtin_amdgcn_mfma_f32_16x16x32_bf16(a[mt], b[g], acc[mt][g], 0, 0, 0);
    }
    // next chunk's DMAs were covered by this chunk's MFMA; pay only the residual
    asm volatile("s_waitcnt vmcnt(0)" ::: "memory");
    __syncthreads();
  }
  #undef STAGE_A
  #undef STAGE_W

  // in-register LSTM epilogue: lane (q,c) per (mt,r): cell = mt*16+4q+r, feat = wf*16+c
  const float swc = swp[w * 16 + c];
  const bool last = (step == NSTEPS - 1);
  float* pt = (float*)abuf;  // [8 waves][64 cells] score partials (reuse A buffers)
  #pragma unroll
  for (int mt = 0; mt < 4; ++mt) {
    #pragma unroll
    for (int r = 0; r < 4; ++r) {
      const int cl = mt * 16 + 4 * q + r;
      const int cell = cb + cl;
      const float ig = sigm(acc[mt][0][r]);
      const float fg = sigm(acc[mt][1][r]);
      const float gg = tanha(acc[mt][2][r]);
      const float og = sigm(acc[mt][3][r]);
      u16* rcp = rc + (size_t)cell * HID + w * 16 + c;
      const float c0 = (step == 0) ? 0.f : bf2f(rcp[0]);
      const float nc = fg * c0 + ig * gg;
      const float nhv = og * tanha(nc);
      if (!last) {
        rcp[0] = f2bf(nc);
        h[(size_t)cell * HID + w * 16 + c] = f2bf(nhv);
      }
      float v = nhv * swc;  // score partial, reduce over c (16 feats)
      v += __shfl_xor(v, 1); v += __shfl_xor(v, 2);
      v += __shfl_xor(v, 4); v += __shfl_xor(v, 8);
      if (c == 0) pt[w * 64 + cl] = v;
    }
  }
  __syncthreads();
  if (tid < 64) {
    float s = 0.f;
    #pragma unroll
    for (int ww = 0; ww < 8; ++ww) s += pt[ww * 64 + tid];
    out[step * CELLS + cb + tid] = s;
  }
}

extern "C" void kernel_launch(void* const* d_in, const int* in_sizes, int n_in,
                              void* d_out, int out_size, void* d_ws, size_t ws_size,
                              hipStream_t stream)
{
  const int* q      = (const int*)d_in[0];
  const int* esrc   = (const int*)d_in[1];
  const int* edst   = (const int*)d_in[2];
  const float* embed= (const float*)d_in[3];
  const float* W0   = (const float*)d_in[4];
  const float* b0   = (const float*)d_in[5];
  const float* W1   = (const float*)d_in[6];
  const float* b1   = (const float*)d_in[7];
  const float* W2   = (const float*)d_in[8];
  const float* b2   = (const float*)d_in[9];
  const float* W3   = (const float*)d_in[10];
  const float* b3   = (const float*)d_in[11];
  const float* Wih  = (const float*)d_in[12];
  const float* Whh  = (const float*)d_in[13];
  const float* sw   = (const float*)d_in[14];

  char* ws = (char*)d_ws;
  size_t off = 0;
  auto alloc = [&](size_t bytes) {
    void* p = ws + off;
    off += (bytes + 255) & ~(size_t)255;
    return p;
  };
  u16*   h    = (u16*)  alloc((size_t)CELLS * HID * 2);
  u16*   xb   = (u16*)  alloc((size_t)CELLS * HID * 2);
  u16*   rc   = (u16*)  alloc((size_t)CELLS * HID * 2);  // bf16 carry
  u16*   m0   = (u16*)  alloc((size_t)CELLS * HID * 2);  // bf16; m1 contiguous after
  u16*   m1   = (u16*)  alloc((size_t)CELLS * HID * 2);
  u16*   W0b  = (u16*)  alloc(2 * 128 * 256 * 2);
  u16*   W123b= (u16*)  alloc((size_t)3 * 2 * 128 * 128 * 2);  // layers 1..3 contiguous
  u16*   Wcb  = (u16*)  alloc(512 * 512 * 2);  // Wcb2 chunk-swizzled layout
  float* bp   = (float*)alloc(4 * 256 * 4);
  u16*   embp = (u16*)  alloc(384 * 2);
  float* swp  = (float*)alloc(128 * 4);
  u16*   zrow = (u16*)  alloc(128 * 2);  // 256B zero row (step-0 rh source)
  // sort workspace
  int*   counts = (int*)alloc((size_t)2 * CELLS * 4);
  int*   Sarr   = (int*)alloc(((size_t)2 * CELLS + 1) * 4);
  int*   fill   = (int*)alloc((size_t)2 * CELLS * 4);
  int*   btot   = (int*)alloc(192 * 4);
  int*   boffs  = (int*)alloc(192 * 4);
  int*   ssrc   = (int*)alloc((size_t)2 * NE * 4);
  int*   sdst   = (int*)alloc((size_t)2 * NE * 4);
  // boundary side buffers
  int*   side_dst  = (int*)  alloc((size_t)2 * NWIN * 2 * 4);
  float* side_part = (float*)alloc((size_t)2 * NWIN * 2 * 128 * 4);

  prep_kernel<<<1670, 256, 0, stream>>>(W0, W1, W2, W3, b0, b1, b2, b3, Wih, Whh, embed, sw,
                                        W0b, W123b, Wcb, bp, embp, swp);
  init_kernel<<<(CELLS * HID) / 256, 256, 0, stream>>>(q, embp, xb, h);

  // dst-sort both edge types
  hipMemsetAsync(counts, 0, (size_t)2 * CELLS * 4, stream);
  hipMemsetAsync(fill, 0, (size_t)2 * CELLS * 4, stream);
  hist_kernel<<<(2 * NE + 255) / 256, 256, 0, stream>>>(edst, counts);
  scan1_kernel<<<192, 1024, 0, stream>>>(counts, Sarr, btot);
  scan2_kernel<<<1, 256, 0, stream>>>(btot, boffs, Sarr);
  scan3_kernel<<<192, 1024, 0, stream>>>(Sarr, boffs);
  scatter_kernel<<<(2 * NE + 255) / 256, 256, 0, stream>>>(esrc, edst, Sarr, fill, ssrc, sdst);

  // m zeroing hoisted out of the step loop: every dst with >=1 edge gets its full row
  // rewritten each step (interior flush or fixup); zero-degree rows stay zero. side_dst
  // values are step-invariant (same sorted graph), so one 0xFF fill suffices.
  hipMemsetAsync(m0, 0, (size_t)2 * CELLS * HID * 2, stream);        // m0+m1 (bf16)
  hipMemsetAsync(side_dst, 0xFF, (size_t)2 * NWIN * 2 * 4, stream);  // dst = -1
  hipMemsetAsync(zrow, 0, 128 * 2, stream);                          // zero rh row

  for (int step = 0; step < NSTEPS; ++step) {
    msg_kernel<<<dim3((NE + 511) / 512, 2), 512, 0, stream>>>(h, ssrc, sdst, Sarr,
                                                              W0b, W123b, bp,
                                                              m0, m1, side_dst, side_part);
    fixup_kernel<<<2 * NWIN, 128, 0, stream>>>(Sarr, side_dst, side_part, m0, m1);
    lstm_kernel<<<CELLS / 64, 512, 0, stream>>>(step, xb, m0, m1, h, rc, Wcb, swp, zrow,
                                                (float*)d_out);
  }
}

// Round 10
// 674.213 us; speedup vs baseline: 1.1403x; 1.0415x over previous
//
#include <hip/hip_runtime.h>

#define HID 128
#define CELLS 98304
#define NE 250000
#define NSTEPS 2
#define NWIN 3912  // 64-edge windows per edge type = 489 blocks * 8 waves

typedef __attribute__((ext_vector_type(8))) short short8;
typedef __attribute__((ext_vector_type(4))) float f32x4;
typedef __attribute__((ext_vector_type(4))) unsigned int u32x4;
typedef unsigned short u16;

// pi permutation: pi-slot s <-> natural col permf(s)
__device__ __forceinline__ int permf(int s) { return ((s & 7) << 4) | (s >> 3); }
// m storage position p: half = p>>6, lane = p&63,
// pi-slot = (lane>>2)*8 + half*4 + (lane&3); natural col = permf(slot)
__device__ __forceinline__ int nat_of_pos(int p) {
  int l = p & 63, hf = p >> 6;
  int slot = ((l >> 2) << 3) + (hf << 2) + (l & 3);
  return ((slot & 7) << 4) | (slot >> 3);
}

__device__ __forceinline__ u16 f2bf(float f) {
  unsigned int u = __builtin_bit_cast(unsigned int, f);
  u += 0x7fffu + ((u >> 16) & 1u);
  return (u16)(u >> 16);
}
__device__ __forceinline__ float bf2f(u16 s) {
  unsigned int u = ((unsigned int)s) << 16;
  return __builtin_bit_cast(float, u);
}
// packed f32x2 -> bf16x2 (RNE), lo -> D[15:0], hi -> D[31:16]
__device__ __forceinline__ unsigned int cvtpk_bf16(float lo, float hi) {
  unsigned int r;
  asm("v_cvt_pk_bf16_f32 %0, %1, %2" : "=v"(r) : "v"(lo), "v"(hi));
  return r;
}
__device__ __forceinline__ float sigm(float x) { return 1.f / (1.f + __expf(-x)); }
__device__ __forceinline__ float tanha(float x) { return 1.f - 2.f / (__expf(2.f * x) + 1.f); }

// zero-register DMA: 16B per lane, global(per-lane addr) -> LDS (wave-uniform base + lane*16)
__device__ __forceinline__ void gload_lds16(const u16* g, u16* l) {
  __builtin_amdgcn_global_load_lds(
      (const __attribute__((address_space(1))) unsigned int*)(const void*)g,
      (__attribute__((address_space(3))) unsigned int*)(void*)l, 16, 0, 0);
}

// cooperative 16KB weight-chunk stage (msg): 512 threads x 2 insts x 16B, linear
__device__ __forceinline__ void stage_w(const u16* __restrict__ ws, u16* wl, int w, int lane) {
  #pragma unroll
  for (int i = 0; i < 2; ++i)
    gload_lds16(ws + i * 4096 + w * 512 + lane * 8, wl + i * 4096 + w * 512);
}

// ---------------- prep: bf16-convert weights ----------------
// W0b: [et][chunk t=0..3][n=128][s=64] -- K-chunks of 64, XOR-swizzled within chunk:
//   position group g' (0..7) of row n holds natural k-group g'^(n&7) of chunk t.
//   t=0,1: src half (k 0..127), t=2,3: dst half (k 128..255). Natural K (h order).
// W123b: [l-1][et][half hh][n][s=64], same per-chunk swizzle, K pi-permuted (tile order).
// Wcb2: [kc=0..7][n=0..511][g'=0..7][j=0..7] -- lstm gates weights in K-chunks of
//   64, XOR-swizzled within chunk (position g' of row n holds natural chunk-group
//   g'^(n&7)); K semantics: [Wih(x | m0 | m1) | Whh] with m-blocks in m-storage order.
__global__ void prep_kernel(
    const float* __restrict__ W0, const float* __restrict__ W1,
    const float* __restrict__ W2, const float* __restrict__ W3,
    const float* __restrict__ b0, const float* __restrict__ b1,
    const float* __restrict__ b2, const float* __restrict__ b3,
    const float* __restrict__ Wih, const float* __restrict__ Whh,
    const float* __restrict__ embed, const float* __restrict__ sw,
    u16* __restrict__ W0b, u16* __restrict__ W123b,
    u16* __restrict__ Wcb, float* __restrict__ bp,
    u16* __restrict__ embp, float* __restrict__ swp)
{
  int idx = blockIdx.x * 256 + threadIdx.x;
  if (idx < 65536) {  // W0b swizzled chunks
    int et = idx >> 15, t = (idx >> 13) & 3, n = (idx >> 6) & 127, s = idx & 63;
    int g = s >> 3, j = s & 7;
    int gn = g ^ (n & 7);
    W0b[idx] = f2bf(W0[(et * 128 + n) * 256 + t * 64 + gn * 8 + j]);
    return;
  }
  idx -= 65536;
  if (idx < 98304) {  // W123b swizzled half-chunks, K pi-permuted
    int which = idx >> 15, r = idx & 32767;
    int et = r >> 14, hh = (r >> 13) & 1, n = (r >> 6) & 127, s = r & 63;
    int g = s >> 3, j = s & 7;
    int gn = g ^ (n & 7);
    const float* W = which == 0 ? W1 : (which == 1 ? W2 : W3);
    W123b[which * 32768 + r] = f2bf(W[(et * 128 + n) * 128 + permf(hh * 64 + gn * 8 + j)]);
    return;
  }
  idx -= 98304;
  if (idx < 262144) {  // Wcb2 chunk-swizzled lstm weights
    int kc = idx >> 15, r = idx & 32767;
    int n = r >> 6, s = r & 63;
    int gp = s >> 3, j = s & 7;
    int k = kc * 64 + ((gp ^ (n & 7)) << 3) + j;   // natural concat-K position
    int blk = k >> 7, s7 = k & 127;
    int k7 = (blk == 1 || blk == 2) ? nat_of_pos(s7) : s7;  // x / rh natural
    float v = (blk < 3) ? Wih[n * 384 + blk * 128 + k7] : Whh[n * 128 + k7];
    Wcb[idx] = f2bf(v);
    return;
  }
  idx -= 262144;
  if (idx < 1024) {  // biases [layer 0..3][et][slot] pi-order
    int l = idx >> 8, r = idx & 255;
    int et = r >> 7, s = r & 127;
    const float* b = l == 0 ? b0 : (l == 1 ? b1 : (l == 2 ? b2 : b3));
    bp[idx] = b[et * 128 + permf(s)];
    return;
  }
  idx -= 1024;
  if (idx < 384) {  // embed natural bf16
    embp[idx] = f2bf(embed[idx]);
    return;
  }
  idx -= 384;
  if (idx < 128) swp[idx] = sw[idx];
}

// ---------------- init: x = embed[q] (natural, bf16), h = x (rc untouched:
// step 0 never reads it) ----------------
__global__ void init_kernel(const int* __restrict__ q, const u16* __restrict__ embp,
                            u16* __restrict__ xb, u16* __restrict__ h)
{
  int idx = blockIdx.x * 256 + threadIdx.x;
  int c = idx >> 7, s = idx & 127;
  u16 v = embp[q[c] * 128 + s];
  xb[idx] = v;
  h[idx] = v;
}

// ---------------- dst-sort pipeline: hist -> scan (2-level) -> scatter ----------------
__global__ void hist_kernel(const int* __restrict__ edst, int* __restrict__ counts)
{
  int idx = blockIdx.x * 256 + threadIdx.x;
  if (idx >= 2 * NE) return;
  int et = (idx >= NE) ? 1 : 0;
  atomicAdd(&counts[et * CELLS + edst[idx]], 1);
}

__global__ void scan1_kernel(const int* __restrict__ counts, int* __restrict__ S,
                             int* __restrict__ btot)
{
  __shared__ int sh[1024];
  const int t = threadIdx.x, b = blockIdx.x;
  const int i = b * 1024 + t;
  int v = counts[i];
  sh[t] = v;
  __syncthreads();
  int acc = v;
  for (int off = 1; off < 1024; off <<= 1) {
    int add = (t >= off) ? sh[t - off] : 0;
    __syncthreads();
    acc += add;
    sh[t] = acc;
    __syncthreads();
  }
  S[i] = acc - v;  // block-local exclusive
  if (t == 1023) btot[b] = acc;
}

__global__ void scan2_kernel(const int* __restrict__ btot, int* __restrict__ boffs,
                             int* __restrict__ S)
{
  __shared__ int sh[256];
  const int t = threadIdx.x;
  int v = (t < 192) ? btot[t] : 0;
  sh[t] = v;
  __syncthreads();
  int acc = v;
  for (int off = 1; off < 256; off <<= 1) {
    int add = (t >= off) ? sh[t - off] : 0;
    __syncthreads();
    acc += add;
    sh[t] = acc;
    __syncthreads();
  }
  if (t < 192) boffs[t] = acc - v;
  if (t == 0) S[2 * CELLS] = 2 * NE;
}

__global__ void scan3_kernel(int* __restrict__ S, const int* __restrict__ boffs)
{
  const int i = blockIdx.x * 1024 + threadIdx.x;
  S[i] += boffs[blockIdx.x];
}

__global__ void scatter_kernel(const int* __restrict__ esrc, const int* __restrict__ edst,
                               const int* __restrict__ S, int* __restrict__ fill,
                               int* __restrict__ ssrc, int* __restrict__ sdst)
{
  int idx = blockIdx.x * 256 + threadIdx.x;
  if (idx >= 2 * NE) return;
  int et = (idx >= NE) ? 1 : 0;
  int d = edst[idx];
  int pos = atomicAdd(&fill[et * CELLS + d], 1);
  int slot = S[et * CELLS + d] - et * NE + pos;  // et-local sorted slot
  sdst[et * NE + slot] = d;
  ssrc[et * NE + slot] = esrc[idx];
}

// bias + relu + pack-transpose into swizzled per-wave LDS A-tile (pitch 128, 8-col XOR
// swizzle). Packed conversion via cvt_pk (R6).
__device__ __forceinline__ void bias_relu_store(f32x4 (&acc)[4][8], const float* __restrict__ bl,
                                                u16* __restrict__ ab, int q, int c)
{
  float bias[8];
  #pragma unroll
  for (int j = 0; j < 8; ++j) bias[j] = bl[c * 8 + j];
  #pragma unroll
  for (int mt = 0; mt < 4; ++mt) {
    #pragma unroll
    for (int r = 0; r < 4; ++r) {
      const int rowl = mt * 16 + 4 * q + r;
      u32x4 t;
      #pragma unroll
      for (int p = 0; p < 4; ++p) {
        float v0 = acc[mt][2 * p][r] + bias[2 * p];
        float v1 = acc[mt][2 * p + 1][r] + bias[2 * p + 1];
        v0 = v0 > 0.f ? v0 : 0.f;
        v1 = v1 > 0.f ? v1 : 0.f;
        t[p] = cvtpk_bf16(v0, v1);
      }
      *(u32x4*)(ab + rowl * 128 + ((c ^ (rowl & 15)) << 3)) = t;
    }
  }
}

// ---------------- fused 4-layer edge MLP + sorted segmented-sum scatter ----------------
// Parked at the measured-best R6 config (8-wave blocks, 64-edge windows, 10-chunk
// 2-deep wbuf pipeline, cvt_pk packing): ~153us/dispatch. Unchanged this round.
__launch_bounds__(512, 2)
__global__ void msg_kernel(
    const u16* __restrict__ h,
    const int* __restrict__ ssrc, const int* __restrict__ sdst,
    const int* __restrict__ S,
    const u16* __restrict__ W0b, const u16* __restrict__ W123b,
    const float* __restrict__ bp,
    u16* __restrict__ m0, u16* __restrict__ m1,
    int* __restrict__ side_dst, float* __restrict__ side_part)
{
  __shared__ u16 abuf[8][64 * 128];   // 128KB: wave-private A-tiles, XOR-swizzled
  __shared__ u16 wbuf[2][128 * 64];   // 32KB: double-buffered weight chunk [n=128][k=64]
  const int et = blockIdx.y;
  const int tid = threadIdx.x;
  const int w = tid >> 6, lane = tid & 63, q = lane >> 4, c = lane & 15;
  const int ebase = blockIdx.x * 512 + w * 64;  // et-local sorted slot base for this wave
  const int win = blockIdx.x * 8 + w;
  const int* __restrict__ src = ssrc + et * NE;
  const int* __restrict__ dst = sdst + et * NE;
  u16* __restrict__ msgs = (et == 0) ? m0 : m1;
  u16* ab = abuf[w];

  // per-lane src row for DMA staging; per-lane dst rows for register gathers
  int eS = ebase + lane;
  if (eS >= NE) eS = NE - 1;
  const int srow = src[eS];

  int rowD[4];
  #pragma unroll
  for (int mt = 0; mt < 4; ++mt) {
    int e = ebase + mt * 16 + c;
    if (e >= NE) e = NE - 1;
    rowD[mt] = dst[e];
  }

  // issue 16 zero-register DMA gathers: h[src] rows -> own swizzled LDS tile.
  // position (row r, group cg) holds natural group cg ^ (r&15).
  #pragma unroll
  for (int i = 0; i < 16; ++i) {
    const int r = i * 4 + (lane >> 4);
    const int grow = __shfl(srow, r);
    const int cg = lane & 15;
    gload_lds16(h + (size_t)grow * 128 + ((cg ^ (r & 15)) << 3), ab + i * 512);
  }
  // chunk 0 (W0 t=2) into wbuf[0]; nobody reads wbuf before the prologue barrier
  stage_w(W0b + (et * 4 + 2) * 8192, wbuf[0], w, lane);

  // run structure (wave-uniform masks). Cross-lane ops unconditional.
  const int eL = ebase + lane;
  const int dval = (eL < NE) ? dst[eL] : -1;
  int rpS = 0, rpE = 0;
  if (dval >= 0) {
    rpS = S[et * CELLS + dval] - et * NE;
    rpE = S[et * CELLS + dval + 1] - et * NE;
  }
  const int dlagged = __shfl_up(dval, 1);          // all 64 lanes active
  const bool headp = (lane == 0) | (dval != dlagged);
  const unsigned long long tails = (__ballot(headp) >> 1) | (1ull << 63);
  const unsigned long long intmask = __ballot(dval >= 0 && rpS >= ebase && rpE <= ebase + 64);

  const f32x4 zf = {0.f, 0.f, 0.f, 0.f};
  f32x4 acc[4][8];
  #pragma unroll
  for (int mt = 0; mt < 4; ++mt)
    #pragma unroll
    for (int nt = 0; nt < 8; ++nt) acc[mt][nt] = zf;

  asm volatile("s_waitcnt vmcnt(0)" ::: "memory");  // A-DMAs + chunk 0 landed
  __syncthreads();

  // ---- 10-chunk pipelined K-loop ----
  #pragma unroll 1
  for (int i = 0; i < 10; ++i) {
    // stage next chunk into the buffer whose readers finished at the previous barrier
    if (i < 9) {
      const int j = i + 1;
      const u16* wsrc;
      if (j < 4) {
        const int t = (j < 2) ? (j + 2) : (j - 2);
        wsrc = W0b + (et * 4 + t) * 8192;
      } else {
        const int li = j - 4;  // (l-1)*2 + hh
        wsrc = W123b + (li >> 1) * 32768 + et * 16384 + (li & 1) * 8192;
      }
      stage_w(wsrc, wbuf[j & 1], w, lane);
    }
    // at the start of each layer chunk-pair: flush previous layer into own A-tile
    if (i >= 4 && !(i & 1)) {
      bias_relu_store(acc, bp + ((i - 4) >> 1) * 256 + et * 128, ab, q, c);
      #pragma unroll
      for (int mt = 0; mt < 4; ++mt)
        #pragma unroll
        for (int nt = 0; nt < 8; ++nt) acc[mt][nt] = zf;
    }
    const u16* wb = wbuf[i & 1];
    #pragma unroll
    for (int ks = 0; ks < 2; ++ks) {
      short8 a[4], b[8];
      if (i < 2) {  // dst half of L0: register gathers (sorted runs -> cache hits)
        const int kqh = i * 64 + ks * 32 + q * 8;
        #pragma unroll
        for (int mt = 0; mt < 4; ++mt)
          a[mt] = *(const short8*)(h + (size_t)rowD[mt] * HID + kqh);
      } else {      // src half of L0 / layers 1-3: own swizzled A-tile
        const int blk = (i & 1) * 8 + ks * 4 + q;
        #pragma unroll
        for (int mt = 0; mt < 4; ++mt) {
          const int row = mt * 16 + c;
          a[mt] = *(const short8*)(ab + row * 128 + ((blk ^ c) << 3));
        }
      }
      #pragma unroll
      for (int nt = 0; nt < 8; ++nt)
        b[nt] = *(const short8*)(wb + (nt * 16 + c) * 64 + (((ks * 4 + q) ^ (c & 7)) << 3));
      #pragma unroll
      for (int mt = 0; mt < 4; ++mt)
        #pragma unroll
        for (int nt = 0; nt < 8; ++nt)
          acc[mt][nt] = __builtin_amdgcn_mfma_f32_16x16x32_bf16(a[mt], b[nt], acc[mt][nt], 0, 0, 0);
    }
    // next chunk's DMA latency was covered by this compute; pay only the residual
    asm volatile("s_waitcnt vmcnt(0)" ::: "memory");
    __syncthreads();
  }

  // layer-3 epilogue: +bias into fp32 fab (two 64-feature passes), column scan; interior
  // flush = 128B coalesced bf16 store; boundary flush = fp32 partial to side buffer.
  float bias[8];
  #pragma unroll
  for (int j = 0; j < 8; ++j) bias[j] = bp[3 * 256 + et * 128 + c * 8 + j];

  float* fab = (float*)ab;  // 64 rows x 64 feature-slots fp32 (16KB, wave-private)
  #pragma unroll
  for (int half = 0; half < 2; ++half) {
    #pragma unroll
    for (int mt = 0; mt < 4; ++mt) {
      #pragma unroll
      for (int r = 0; r < 4; ++r) {
        const int row = mt * 16 + 4 * q + r;
        f32x4 t;
        #pragma unroll
        for (int nti = 0; nti < 4; ++nti)
          t[nti] = acc[mt][half * 4 + nti][r] + bias[half * 4 + nti];
        *(f32x4*)(fab + row * 64 + c * 4) = t;
      }
    }
    float run = 0.f;
    int jstart = 0;
    #pragma unroll 1
    for (int jb = 0; jb < 64; jb += 8) {
      #pragma unroll
      for (int u = 0; u < 8; ++u) {
        const int j = jb + u;
        run += fab[j * 64 + lane];
        if ((tails >> j) & 1) {  // wave-uniform flush at run tail
          const int d = __builtin_amdgcn_readlane(dval, j);
          if (d >= 0) {
            if ((intmask >> j) & 1) {
              msgs[(size_t)d * HID + half * 64 + lane] = f2bf(run);
            } else {
              const int slot = (jstart == 0) ? 0 : 1;  // only first/last runs can straddle
              const size_t sb = ((size_t)et * NWIN + win) * 2 + slot;
              side_part[sb * 128 + half * 64 + lane] = run;
              if (lane == 0 && half == 0) side_dst[sb] = d;
            }
          }
          run = 0.f;
          jstart = j + 1;
        }
      }
    }
  }
}

// ---------------- boundary fixup: owner window sums fp32 partials, writes bf16 m ------
__global__ void fixup_kernel(const int* __restrict__ S,
                             const int* __restrict__ side_dst,
                             const float* __restrict__ side_part,
                             u16* __restrict__ m0, u16* __restrict__ m1)
{
  const int b = blockIdx.x;           // et*NWIN + win
  const int et = b / NWIN, win = b - et * NWIN;
  const int t = threadIdx.x;          // 0..127
  u16* __restrict__ m = et ? m1 : m0;
  #pragma unroll
  for (int s = 0; s < 2; ++s) {
    const int d = side_dst[b * 2 + s];
    if (d < 0) continue;
    const int r0 = S[et * CELLS + d] - et * NE;
    if ((r0 >> 6) != win) continue;   // not the owner window (64-edge windows)
    const int w1 = (S[et * CELLS + d + 1] - et * NE - 1) >> 6;
    float sum = 0.f;
    for (int wi = win; wi <= w1; ++wi) {
      const int base = (et * NWIN + wi) * 2;
      if (side_dst[base + 0] == d) sum += side_part[(size_t)(base + 0) * 128 + t];
      if (side_dst[base + 1] == d) sum += side_part[(size_t)(base + 1) * 128 + t];
    }
    m[(size_t)d * HID + t] = f2bf(sum);
  }
}

// ---------------- fused LSTM: gates GEMM (K=512) + in-register activations + score -------
// R10: M=128 cell-tiles (768 blocks). R9's rebuild was NEUTRAL -> diagnosis: both old
// and new lstm are W-TRAFFIC bound (every block re-stages the full 512KB Wcb; 1536
// blocks x 512KB = 786MB of L2->LDS movement). Doubling the M-tile halves W traffic
// (768 x 512KB = 393MB) and doubles MFMA per staged chunk (better stage/compute
// overlap in the same 2-deep pipeline). acc[8][4] = 128 AGPR, fine at 2 waves/SIMD.
// LDS: wbuf 2x64KB + abuf 2x16KB = 160KB exactly (R6 msg already runs 160KB blocks).
// Delta-attribution: nothing else changed this round, so dtotal = 2 x dlstm.
__launch_bounds__(512, 2)
__global__ void lstm_kernel(
    const int step,
    const u16* __restrict__ xb, const u16* __restrict__ mm0, const u16* __restrict__ mm1,
    u16* __restrict__ h, u16* __restrict__ rc,
    const u16* __restrict__ Wcb, const float* __restrict__ swp,
    const u16* __restrict__ zrow,
    float* __restrict__ out)
{
  __shared__ u16 wbuf[2][512 * 64];  // 128KB: W K-chunks [n=512][8 grp x 8], swizzled
  __shared__ u16 abuf[2][128 * 64];  // 32KB: A K-chunks [cell=128][8 grp x 8], swizzled
  const int tid = threadIdx.x;
  const int cb = blockIdx.x * 128;
  const int w = tid >> 6, lane = tid & 63, q = lane >> 4, c = lane & 15;

  const f32x4 zf = {0.f, 0.f, 0.f, 0.f};
  f32x4 acc[8][4];  // [cell-tile][gate] -- 128 AGPR
  #pragma unroll
  for (int mt = 0; mt < 8; ++mt)
    #pragma unroll
    for (int g = 0; g < 4; ++g) acc[mt][g] = zf;

  // A-chunk stage (16KB): two sub-passes i=0,1; idx=i*512+tid -> LDS slot idx*16B =
  // (cell cl=idx>>3, group pos lg=idx&7); source col within the 128-col source span
  // = (kc&1)*64 + ((lg ^ (cl&7))<<3).
  #define STAGE_A(kc, buf)                                                           \
    {                                                                                \
      _Pragma("unroll")                                                              \
      for (int i = 0; i < 2; ++i) {                                                  \
        const int idx = i * 512 + tid;                                               \
        const int cl = idx >> 3, lg = idx & 7;                                       \
        const int col = (((kc) & 1) << 6) + ((lg ^ (cl & 7)) << 3);                  \
        const int sel = (kc) >> 1;                                                   \
        const u16* srcp;                                                             \
        if (sel == 0)      srcp = xb  + (size_t)(cb + cl) * 128 + col;               \
        else if (sel == 1) srcp = mm0 + (size_t)(cb + cl) * 128 + col;               \
        else if (sel == 2) srcp = mm1 + (size_t)(cb + cl) * 128 + col;               \
        else srcp = (step == 0) ? (zrow + col) : (h + (size_t)(cb + cl) * 128 + col);\
        gload_lds16(srcp, abuf[buf] + i * 4096 + w * 512);                           \
      }                                                                              \
    }
  // W-chunk stage: 64KB linear copy from pre-swizzled Wcb2 chunk kc (8 insts/thread)
  #define STAGE_W(kc, buf)                                                           \
    {                                                                                \
      _Pragma("unroll")                                                              \
      for (int i = 0; i < 8; ++i)                                                    \
        gload_lds16(Wcb + (size_t)(kc) * 32768 + i * 4096 + tid * 8,                 \
                    wbuf[buf] + i * 4096 + w * 512);                                 \
    }

  STAGE_A(0, 0);
  STAGE_W(0, 0);
  asm volatile("s_waitcnt vmcnt(0)" ::: "memory");
  __syncthreads();

  #pragma unroll 1
  for (int kc = 0; kc < 8; ++kc) {
    if (kc < 7) {
      STAGE_A(kc + 1, (kc + 1) & 1);
      STAGE_W(kc + 1, (kc + 1) & 1);
    }
    const u16* ac = abuf[kc & 1];
    const u16* wc = wbuf[kc & 1];
    #pragma unroll
    for (int kk = 0; kk < 2; ++kk) {
      const int lg = kk * 4 + q;
      short8 a[8], b[4];
      #pragma unroll
      for (int mt = 0; mt < 8; ++mt) {
        const int row = mt * 16 + c;
        a[mt] = *(const short8*)(ac + row * 64 + ((lg ^ (row & 7)) << 3));
      }
      #pragma unroll
      for (int g = 0; g < 4; ++g) {
        const int n = g * 128 + w * 16 + c;
        b[g] = *(const short8*)(wc + n * 64 + ((lg ^ (n & 7)) << 3));
      }
      #pragma unroll
      for (int mt = 0; mt < 8; ++mt)
        #pragma unroll
        for (int g = 0; g < 4; ++g)
          acc[mt][g] = __builtin_amdgcn_mfma_f32_16x16x32_bf16(a[mt], b[g], acc[mt][g], 0, 0, 0);
    }
    // next chunk's DMAs were covered by this chunk's MFMA; pay only the residual
    asm volatile("s_waitcnt vmcnt(0)" ::: "memory");
    __syncthreads();
  }
  #undef STAGE_A
  #undef STAGE_W

  // in-register LSTM epilogue: lane (q,c) per (mt,r): cell = mt*16+4q+r, feat = w*16+c
  const float swc = swp[w * 16 + c];
  const bool last = (step == NSTEPS - 1);
  float* pt = (float*)abuf;  // [8 waves][128 cells] score partials (reuse A buffers)
  #pragma unroll
  for (int mt = 0; mt < 8; ++mt) {
    #pragma unroll
    for (int r = 0; r < 4; ++r) {
      const int cl = mt * 16 + 4 * q + r;
      const int cell = cb + cl;
      const float ig = sigm(acc[mt][0][r]);
      const float fg = sigm(acc[mt][1][r]);
      const float gg = tanha(acc[mt][2][r]);
      const float og = sigm(acc[mt][3][r]);
      u16* rcp = rc + (size_t)cell * HID + w * 16 + c;
      const float c0 = (step == 0) ? 0.f : bf2f(rcp[0]);
      const float nc = fg * c0 + ig * gg;
      const float nhv = og * tanha(nc);
      if (!last) {
        rcp[0] = f2bf(nc);
        h[(size_t)cell * HID + w * 16 + c] = f2bf(nhv);
      }
      float v = nhv * swc;  // score partial, reduce over c (16 feats)
      v += __shfl_xor(v, 1); v += __shfl_xor(v, 2);
      v += __shfl_xor(v, 4); v += __shfl_xor(v, 8);
      if (c == 0) pt[w * 128 + cl] = v;
    }
  }
  __syncthreads();
  if (tid < 128) {
    float s = 0.f;
    #pragma unroll
    for (int ww = 0; ww < 8; ++ww) s += pt[ww * 128 + tid];
    out[step * CELLS + cb + tid] = s;
  }
}

extern "C" void kernel_launch(void* const* d_in, const int* in_sizes, int n_in,
                              void* d_out, int out_size, void* d_ws, size_t ws_size,
                              hipStream_t stream)
{
  const int* q      = (const int*)d_in[0];
  const int* esrc   = (const int*)d_in[1];
  const int* edst   = (const int*)d_in[2];
  const float* embed= (const float*)d_in[3];
  const float* W0   = (const float*)d_in[4];
  const float* b0   = (const float*)d_in[5];
  const float* W1   = (const float*)d_in[6];
  const float* b1   = (const float*)d_in[7];
  const float* W2   = (const float*)d_in[8];
  const float* b2   = (const float*)d_in[9];
  const float* W3   = (const float*)d_in[10];
  const float* b3   = (const float*)d_in[11];
  const float* Wih  = (const float*)d_in[12];
  const float* Whh  = (const float*)d_in[13];
  const float* sw   = (const float*)d_in[14];

  char* ws = (char*)d_ws;
  size_t off = 0;
  auto alloc = [&](size_t bytes) {
    void* p = ws + off;
    off += (bytes + 255) & ~(size_t)255;
    return p;
  };
  u16*   h    = (u16*)  alloc((size_t)CELLS * HID * 2);
  u16*   xb   = (u16*)  alloc((size_t)CELLS * HID * 2);
  u16*   rc   = (u16*)  alloc((size_t)CELLS * HID * 2);  // bf16 carry
  u16*   m0   = (u16*)  alloc((size_t)CELLS * HID * 2);  // bf16; m1 contiguous after
  u16*   m1   = (u16*)  alloc((size_t)CELLS * HID * 2);
  u16*   W0b  = (u16*)  alloc(2 * 128 * 256 * 2);
  u16*   W123b= (u16*)  alloc((size_t)3 * 2 * 128 * 128 * 2);  // layers 1..3 contiguous
  u16*   Wcb  = (u16*)  alloc(512 * 512 * 2);  // Wcb2 chunk-swizzled layout
  float* bp   = (float*)alloc(4 * 256 * 4);
  u16*   embp = (u16*)  alloc(384 * 2);
  float* swp  = (float*)alloc(128 * 4);
  u16*   zrow = (u16*)  alloc(128 * 2);  // 256B zero row (step-0 rh source)
  // sort workspace
  int*   counts = (int*)alloc((size_t)2 * CELLS * 4);
  int*   Sarr   = (int*)alloc(((size_t)2 * CELLS + 1) * 4);
  int*   fill   = (int*)alloc((size_t)2 * CELLS * 4);
  int*   btot   = (int*)alloc(192 * 4);
  int*   boffs  = (int*)alloc(192 * 4);
  int*   ssrc   = (int*)alloc((size_t)2 * NE * 4);
  int*   sdst   = (int*)alloc((size_t)2 * NE * 4);
  // boundary side buffers
  int*   side_dst  = (int*)  alloc((size_t)2 * NWIN * 2 * 4);
  float* side_part = (float*)alloc((size_t)2 * NWIN * 2 * 128 * 4);

  prep_kernel<<<1670, 256, 0, stream>>>(W0, W1, W2, W3, b0, b1, b2, b3, Wih, Whh, embed, sw,
                                        W0b, W123b, Wcb, bp, embp, swp);
  init_kernel<<<(CELLS * HID) / 256, 256, 0, stream>>>(q, embp, xb, h);

  // dst-sort both edge types
  hipMemsetAsync(counts, 0, (size_t)2 * CELLS * 4, stream);
  hipMemsetAsync(fill, 0, (size_t)2 * CELLS * 4, stream);
  hist_kernel<<<(2 * NE + 255) / 256, 256, 0, stream>>>(edst, counts);
  scan1_kernel<<<192, 1024, 0, stream>>>(counts, Sarr, btot);
  scan2_kernel<<<1, 256, 0, stream>>>(btot, boffs, Sarr);
  scan3_kernel<<<192, 1024, 0, stream>>>(Sarr, boffs);
  scatter_kernel<<<(2 * NE + 255) / 256, 256, 0, stream>>>(esrc, edst, Sarr, fill, ssrc, sdst);

  // m zeroing hoisted out of the step loop: every dst with >=1 edge gets its full row
  // rewritten each step (interior flush or fixup); zero-degree rows stay zero. side_dst
  // values are step-invariant (same sorted graph), so one 0xFF fill suffices.
  hipMemsetAsync(m0, 0, (size_t)2 * CELLS * HID * 2, stream);        // m0+m1 (bf16)
  hipMemsetAsync(side_dst, 0xFF, (size_t)2 * NWIN * 2 * 4, stream);  // dst = -1
  hipMemsetAsync(zrow, 0, 128 * 2, stream);                          // zero rh row

  for (int step = 0; step < NSTEPS; ++step) {
    msg_kernel<<<dim3((NE + 511) / 512, 2), 512, 0, stream>>>(h, ssrc, sdst, Sarr,
                                                              W0b, W123b, bp,
                                                              m0, m1, side_dst, side_part);
    fixup_kernel<<<2 * NWIN, 128, 0, stream>>>(Sarr, side_dst, side_part, m0, m1);
    lstm_kernel<<<CELLS / 128, 512, 0, stream>>>(step, xb, m0, m1, h, rc, Wcb, swp, zrow,
                                                 (float*)d_out);
  }
}